// Round 1
// baseline (9704.575 us; speedup 1.0000x reference)
//
#include <hip/hip_runtime.h>
#include <math.h>

#define B_SZ 4
#define IN_F 32
#define H1_F 32
#define H2_F 30

__device__ __forceinline__ float sigmoidf_(float x) {
    return 1.f / (1.f + __expf(-x));
}

// ---------------------------------------------------------------------------
// Kernel 1: mean / sum-of-squares of edge_attr (E floats) -> sums[0], sums[1]
// ---------------------------------------------------------------------------
__global__ void __launch_bounds__(256) stats_kernel(const float* __restrict__ ea,
                                                    float* __restrict__ sums, int E) {
    int gid = blockIdx.x * blockDim.x + threadIdx.x;
    int stride = gridDim.x * blockDim.x;
    float v = 0.f, v2 = 0.f;
    for (int i = gid; i < E; i += stride) {
        float a = ea[i];
        v += a;
        v2 += a * a;
    }
    // wave (64-lane) reduction
    for (int off = 32; off > 0; off >>= 1) {
        v  += __shfl_down(v, off);
        v2 += __shfl_down(v2, off);
    }
    __shared__ float s1[4], s2[4];
    int wid = threadIdx.x >> 6;
    int lane = threadIdx.x & 63;
    if (lane == 0) { s1[wid] = v; s2[wid] = v2; }
    __syncthreads();
    if (threadIdx.x == 0) {
        float t1 = s1[0] + s1[1] + s1[2] + s1[3];
        float t2 = s2[0] + s2[1] + s2[2] + s2[3];
        unsafeAtomicAdd(&sums[0], t1);
        unsafeAtomicAdd(&sums[1], t2);
    }
}

// ---------------------------------------------------------------------------
// Kernel 2: per-(edge,batch) MLP + signed atomic scatter into acc (BN x 30)
// ---------------------------------------------------------------------------
__global__ void __launch_bounds__(256) edge_kernel(
    const float* __restrict__ x, const int* __restrict__ ei,
    const float* __restrict__ ea,
    const float* __restrict__ W1, const float* __restrict__ b1,
    const float* __restrict__ W2, const float* __restrict__ b2,
    const float* __restrict__ sums, float* __restrict__ acc, int E, int N) {
    __shared__ float sW1[(2 * IN_F + 1) * H1_F];  // 65*32 row-major [i][j]
    __shared__ float sb1[H1_F];
    __shared__ float sW2[H1_F * H2_F];            // 32*30 row-major [i][j]
    __shared__ float sb2[H2_F];
    for (int i = threadIdx.x; i < (2 * IN_F + 1) * H1_F; i += 256) sW1[i] = W1[i];
    for (int i = threadIdx.x; i < H1_F * H2_F; i += 256) sW2[i] = W2[i];
    if (threadIdx.x < H1_F) sb1[threadIdx.x] = b1[threadIdx.x];
    if (threadIdx.x < H2_F) sb2[threadIdx.x] = b2[threadIdx.x];
    __syncthreads();

    long long gid = (long long)blockIdx.x * 256 + threadIdx.x;
    if (gid >= (long long)B_SZ * E) return;
    int e = (int)(gid >> 2);   // lanes 0..3 share an edge -> broadcast index loads
    int b = (int)(gid & 3);

    int src = ei[e];
    int tgt = ei[E + e];

    float s1 = sums[0], s2 = sums[1];
    float mean = s1 / (float)E;
    float var = (s2 - (float)E * mean * mean) / (float)(E - 1);
    float eav = (ea[e] - mean) * rsqrtf(var);

    // ----- layer 1: h1 = sigmoid([xs, xt, eav] @ W1 + b1) -----
    float h1[H1_F];
#pragma unroll
    for (int j = 0; j < H1_F; j++)
        h1[j] = sb1[j] + eav * sW1[2 * IN_F * H1_F + j];

    const float4* xs4 = (const float4*)(x + ((size_t)b * N + src) * IN_F);
    const float4* xt4 = (const float4*)(x + ((size_t)b * N + tgt) * IN_F);
#pragma unroll
    for (int i4 = 0; i4 < IN_F / 4; i4++) {
        float4 a = xs4[i4];
        float4 c = xt4[i4];
        const float* w_s = &sW1[(i4 * 4) * H1_F];
        const float* w_t = &sW1[(IN_F + i4 * 4) * H1_F];
#pragma unroll
        for (int j = 0; j < H1_F; j++) {
            h1[j] += a.x * w_s[j]            + a.y * w_s[H1_F + j]
                   + a.z * w_s[2 * H1_F + j] + a.w * w_s[3 * H1_F + j]
                   + c.x * w_t[j]            + c.y * w_t[H1_F + j]
                   + c.z * w_t[2 * H1_F + j] + c.w * w_t[3 * H1_F + j];
        }
    }
#pragma unroll
    for (int i = 0; i < H1_F; i++) h1[i] = sigmoidf_(h1[i]);

    // ----- layer 2: h2 = sigmoid(h1 @ W2 + b2) -----
    float h2[H2_F];
#pragma unroll
    for (int j = 0; j < H2_F; j++) h2[j] = sb2[j];
#pragma unroll
    for (int i = 0; i < H1_F; i++) {
        float a = h1[i];
#pragma unroll
        for (int j = 0; j < H2_F; j++) h2[j] += a * sW2[i * H2_F + j];
    }

    // ----- signed scatter -----
    float* at = acc + ((size_t)b * N + tgt) * H2_F;
    float* as = acc + ((size_t)b * N + src) * H2_F;
#pragma unroll
    for (int j = 0; j < H2_F; j++) {
        float hv = sigmoidf_(h2[j]);
        unsafeAtomicAdd(at + j, hv);
        unsafeAtomicAdd(as + j, -hv);
    }
}

// ---------------------------------------------------------------------------
// Kernel 3: out[row] = sigmoid(acc[row] @ W3 + b3), rows = B*N, 30 -> 32
// ---------------------------------------------------------------------------
__global__ void __launch_bounds__(256) final_kernel(const float* __restrict__ acc,
                                                    const float* __restrict__ W3,
                                                    const float* __restrict__ b3,
                                                    float* __restrict__ out, int BN) {
    __shared__ float sW3[H2_F * 32];  // 30x32 row-major
    __shared__ float sb3[32];
    __shared__ float srow[8][H2_F];
    for (int i = threadIdx.x; i < H2_F * 32; i += 256) sW3[i] = W3[i];
    if (threadIdx.x < 32) sb3[threadIdx.x] = b3[threadIdx.x];

    int row0 = blockIdx.x * 8;
    for (int i = threadIdx.x; i < 8 * H2_F; i += 256) {
        int r = i / H2_F, k = i % H2_F;
        int rr = row0 + r;
        srow[r][k] = (rr < BN) ? acc[(size_t)rr * H2_F + k] : 0.f;
    }
    __syncthreads();

    int r = threadIdx.x >> 5;
    int j = threadIdx.x & 31;
    int row = row0 + r;
    if (row < BN) {
        float a = sb3[j];
#pragma unroll
        for (int k = 0; k < H2_F; k++) a += srow[r][k] * sW3[k * 32 + j];
        out[(size_t)row * 32 + j] = sigmoidf_(a);
    }
}

// ---------------------------------------------------------------------------
extern "C" void kernel_launch(void* const* d_in, const int* in_sizes, int n_in,
                              void* d_out, int out_size, void* d_ws, size_t ws_size,
                              hipStream_t stream) {
    const float* x  = (const float*)d_in[0];
    const int*   ei = (const int*)d_in[1];
    const float* ea = (const float*)d_in[2];
    const float* W1 = (const float*)d_in[3];
    const float* b1 = (const float*)d_in[4];
    const float* W2 = (const float*)d_in[5];
    const float* b2 = (const float*)d_in[6];
    const float* W3 = (const float*)d_in[7];
    const float* b3 = (const float*)d_in[8];
    float* out = (float*)d_out;

    const int E  = in_sizes[2];
    const int N  = in_sizes[0] / (B_SZ * IN_F);
    const int BN = B_SZ * N;

    float* acc  = (float*)d_ws;                 // BN * 30 floats
    float* sums = acc + (size_t)BN * H2_F;      // 2 floats

    hipMemsetAsync(d_ws, 0, (size_t)BN * H2_F * sizeof(float) + 2 * sizeof(float),
                   stream);

    stats_kernel<<<256, 256, 0, stream>>>(ea, sums, E);

    long long total = (long long)B_SZ * E;
    int blocks = (int)((total + 255) / 256);
    edge_kernel<<<blocks, 256, 0, stream>>>(x, ei, ea, W1, b1, W2, b2, sums, acc, E, N);

    final_kernel<<<(BN + 7) / 8, 256, 0, stream>>>(acc, W3, b3, out, BN);
}

// Round 2
// 1253.334 us; speedup vs baseline: 7.7430x; 7.7430x over previous
//
#include <hip/hip_runtime.h>
#include <math.h>

#define B_SZ 4
#define IN_F 32
#define H1_F 32
#define H2_F 30

typedef unsigned int uint;
typedef unsigned short ushort;

__device__ __forceinline__ float sigmoidf_(float x) {
    return 1.f / (1.f + __expf(-x));
}

__device__ __forceinline__ ushort f2bf(float f) {
    uint u = __float_as_uint(f);
    uint r = (u + 0x7FFFu + ((u >> 16) & 1u)) >> 16;  // RNE
    return (ushort)r;
}

__device__ __forceinline__ float bf2f(ushort v) {
    return __uint_as_float(((uint)v) << 16);
}

// ---------------------------------------------------------------------------
// Kernel 1: mean / sum-of-squares of edge_attr (E floats) -> sums[0], sums[1]
// ---------------------------------------------------------------------------
__global__ void __launch_bounds__(256) stats_kernel(const float* __restrict__ ea,
                                                    float* __restrict__ sums, int E) {
    int gid = blockIdx.x * blockDim.x + threadIdx.x;
    int stride = gridDim.x * blockDim.x;
    float v = 0.f, v2 = 0.f;
    for (int i = gid; i < E; i += stride) {
        float a = ea[i];
        v += a;
        v2 += a * a;
    }
    for (int off = 32; off > 0; off >>= 1) {
        v  += __shfl_down(v, off);
        v2 += __shfl_down(v2, off);
    }
    __shared__ float s1[4], s2[4];
    int wid = threadIdx.x >> 6;
    int lane = threadIdx.x & 63;
    if (lane == 0) { s1[wid] = v; s2[wid] = v2; }
    __syncthreads();
    if (threadIdx.x == 0) {
        unsafeAtomicAdd(&sums[0], s1[0] + s1[1] + s1[2] + s1[3]);
        unsafeAtomicAdd(&sums[1], s2[0] + s2[1] + s2[2] + s2[3]);
    }
}

// ---------------------------------------------------------------------------
// Kernel 2: histogram of tgt (bucket n) and src (bucket N+n)
// ---------------------------------------------------------------------------
__global__ void __launch_bounds__(256) hist_kernel(const int* __restrict__ ei,
                                                   int* __restrict__ cnt, int E, int N) {
    int e = blockIdx.x * 256 + threadIdx.x;
    if (e < E) {
        atomicAdd(&cnt[ei[E + e]], 1);      // tgt bucket
        atomicAdd(&cnt[N + ei[e]], 1);      // src bucket
    }
}

// ---------------------------------------------------------------------------
// Kernel 3: single-block exclusive scan of cnt[0..n2) -> offs[0..n2], cursor
// ---------------------------------------------------------------------------
__global__ void __launch_bounds__(1024) scan_kernel(const int* __restrict__ cnt,
                                                    int* __restrict__ offs,
                                                    int* __restrict__ cursor, int n2) {
    __shared__ int wsum[16];
    int lane = threadIdx.x & 63;
    int wid = threadIdx.x >> 6;
    int running = 0;
    int iters = (n2 + 1023) >> 10;
    for (int it = 0; it < iters; ++it) {
        int i = (it << 10) + threadIdx.x;
        int v = (i < n2) ? cnt[i] : 0;
        int incl = v;
#pragma unroll
        for (int d = 1; d < 64; d <<= 1) {
            int t = __shfl_up(incl, d);
            if (lane >= d) incl += t;
        }
        if (lane == 63) wsum[wid] = incl;
        __syncthreads();
        int waveoff = 0, tot = 0;
#pragma unroll
        for (int w = 0; w < 16; w++) {
            int xv = wsum[w];
            if (w < wid) waveoff += xv;
            tot += xv;
        }
        int excl = running + waveoff + (incl - v);
        if (i < n2) { offs[i] = excl; cursor[i] = excl; }
        running += tot;
        __syncthreads();
    }
    if (threadIdx.x == 0) offs[n2] = running;
}

// ---------------------------------------------------------------------------
// Kernel 4: scatter edge ids into per-node lists via cursor atomics
// ---------------------------------------------------------------------------
__global__ void __launch_bounds__(256) scatter_kernel(const int* __restrict__ ei,
                                                      int* __restrict__ cursor,
                                                      int* __restrict__ list, int E, int N) {
    int e = blockIdx.x * 256 + threadIdx.x;
    if (e < E) {
        int tgt = ei[E + e];
        int p = atomicAdd(&cursor[tgt], 1);
        list[p] = e;
        int src = ei[e];
        int q = atomicAdd(&cursor[N + src], 1);
        list[q] = e;
    }
}

// ---------------------------------------------------------------------------
// Kernel 5: per-(edge,batch) MLP; writes h as bf16 [e][b][30]
// ---------------------------------------------------------------------------
__global__ void __launch_bounds__(256) edge_mlp_kernel(
    const float* __restrict__ x, const int* __restrict__ ei,
    const float* __restrict__ ea,
    const float* __restrict__ W1, const float* __restrict__ b1,
    const float* __restrict__ W2, const float* __restrict__ b2,
    const float* __restrict__ sums, ushort* __restrict__ h, int E, int N) {
    __shared__ float sW1[(2 * IN_F + 1) * H1_F];
    __shared__ float sb1[H1_F];
    __shared__ float sW2[H1_F * H2_F];
    __shared__ float sb2[H2_F];
    for (int i = threadIdx.x; i < (2 * IN_F + 1) * H1_F; i += 256) sW1[i] = W1[i];
    for (int i = threadIdx.x; i < H1_F * H2_F; i += 256) sW2[i] = W2[i];
    if (threadIdx.x < H1_F) sb1[threadIdx.x] = b1[threadIdx.x];
    if (threadIdx.x < H2_F) sb2[threadIdx.x] = b2[threadIdx.x];
    __syncthreads();

    long long gid = (long long)blockIdx.x * 256 + threadIdx.x;
    if (gid >= (long long)B_SZ * E) return;
    int e = (int)(gid >> 2);
    int b = (int)(gid & 3);

    int src = ei[e];
    int tgt = ei[E + e];

    float s1 = sums[0], s2 = sums[1];
    float mean = s1 / (float)E;
    float var = (s2 - (float)E * mean * mean) / (float)(E - 1);
    float eav = (ea[e] - mean) * rsqrtf(var);

    float h1[H1_F];
#pragma unroll
    for (int j = 0; j < H1_F; j++)
        h1[j] = sb1[j] + eav * sW1[2 * IN_F * H1_F + j];

    const float4* xs4 = (const float4*)(x + ((size_t)b * N + src) * IN_F);
    const float4* xt4 = (const float4*)(x + ((size_t)b * N + tgt) * IN_F);
#pragma unroll
    for (int i4 = 0; i4 < IN_F / 4; i4++) {
        float4 a = xs4[i4];
        float4 c = xt4[i4];
        const float* w_s = &sW1[(i4 * 4) * H1_F];
        const float* w_t = &sW1[(IN_F + i4 * 4) * H1_F];
#pragma unroll
        for (int j = 0; j < H1_F; j++) {
            h1[j] += a.x * w_s[j]            + a.y * w_s[H1_F + j]
                   + a.z * w_s[2 * H1_F + j] + a.w * w_s[3 * H1_F + j]
                   + c.x * w_t[j]            + c.y * w_t[H1_F + j]
                   + c.z * w_t[2 * H1_F + j] + c.w * w_t[3 * H1_F + j];
        }
    }
#pragma unroll
    for (int i = 0; i < H1_F; i++) h1[i] = sigmoidf_(h1[i]);

    float h2[H2_F];
#pragma unroll
    for (int j = 0; j < H2_F; j++) h2[j] = sb2[j];
#pragma unroll
    for (int i = 0; i < H1_F; i++) {
        float a = h1[i];
#pragma unroll
        for (int j = 0; j < H2_F; j++) h2[j] += a * sW2[i * H2_F + j];
    }

    // pack sigmoid(h2) to bf16, 15 dword stores (contiguous 60 B per thread)
    uint* hp = (uint*)(h + ((size_t)e * 4 + b) * H2_F);
#pragma unroll
    for (int q = 0; q < H2_F / 2; q++) {
        uint lo = f2bf(sigmoidf_(h2[2 * q]));
        uint hi = f2bf(sigmoidf_(h2[2 * q + 1]));
        hp[q] = lo | (hi << 16);
    }
}

// ---------------------------------------------------------------------------
// Kernel 6: per-node gather (+tgt list, -src list) + fused W3 matmul+sigmoid
//   block = 256 : two node-groups of 128 threads; t<120 -> (b=t/30, j=t%30)
// ---------------------------------------------------------------------------
__global__ void __launch_bounds__(256) gather_final_kernel(
    const ushort* __restrict__ h, const int* __restrict__ list,
    const int* __restrict__ offs,
    const float* __restrict__ W3, const float* __restrict__ b3,
    float* __restrict__ out, int N) {
    __shared__ float sW3[H2_F * 32];
    __shared__ float sb3[32];
    __shared__ float sacc[2][B_SZ * H2_F];
    for (int i = threadIdx.x; i < H2_F * 32; i += 256) sW3[i] = W3[i];
    if (threadIdx.x < 32) sb3[threadIdx.x] = b3[threadIdx.x];

    int grp = threadIdx.x >> 7;
    int t = threadIdx.x & 127;
    int n = blockIdx.x * 2 + grp;

    float acc = 0.f;
    if (n < N && t < B_SZ * H2_F) {
        int s0 = offs[n], e0 = offs[n + 1];
        int s1 = offs[N + n], e1 = offs[N + n + 1];
        int i = s0;
        for (; i + 4 <= e0; i += 4) {
            int ea_ = list[i], eb_ = list[i + 1], ec_ = list[i + 2], ed_ = list[i + 3];
            acc += bf2f(h[(size_t)ea_ * 120 + t]) + bf2f(h[(size_t)eb_ * 120 + t])
                 + bf2f(h[(size_t)ec_ * 120 + t]) + bf2f(h[(size_t)ed_ * 120 + t]);
        }
        for (; i < e0; i++) acc += bf2f(h[(size_t)list[i] * 120 + t]);
        i = s1;
        for (; i + 4 <= e1; i += 4) {
            int ea_ = list[i], eb_ = list[i + 1], ec_ = list[i + 2], ed_ = list[i + 3];
            acc -= bf2f(h[(size_t)ea_ * 120 + t]) + bf2f(h[(size_t)eb_ * 120 + t])
                 + bf2f(h[(size_t)ec_ * 120 + t]) + bf2f(h[(size_t)ed_ * 120 + t]);
        }
        for (; i < e1; i++) acc -= bf2f(h[(size_t)list[i] * 120 + t]);
    }
    if (t < B_SZ * H2_F) sacc[grp][t] = acc;
    __syncthreads();

    if (n < N) {
        int b = t >> 5;
        int k = t & 31;
        float a = sb3[k];
#pragma unroll
        for (int j = 0; j < H2_F; j++) a += sacc[grp][b * H2_F + j] * sW3[j * 32 + k];
        out[(((size_t)b * N) + n) * 32 + k] = sigmoidf_(a);
    }
}

// ---------------------------------------------------------------------------
// Fallback path (small ws): round-1 atomic kernels
// ---------------------------------------------------------------------------
__global__ void __launch_bounds__(256) edge_kernel_atomic(
    const float* __restrict__ x, const int* __restrict__ ei,
    const float* __restrict__ ea,
    const float* __restrict__ W1, const float* __restrict__ b1,
    const float* __restrict__ W2, const float* __restrict__ b2,
    const float* __restrict__ sums, float* __restrict__ acc, int E, int N) {
    __shared__ float sW1[(2 * IN_F + 1) * H1_F];
    __shared__ float sb1[H1_F];
    __shared__ float sW2[H1_F * H2_F];
    __shared__ float sb2[H2_F];
    for (int i = threadIdx.x; i < (2 * IN_F + 1) * H1_F; i += 256) sW1[i] = W1[i];
    for (int i = threadIdx.x; i < H1_F * H2_F; i += 256) sW2[i] = W2[i];
    if (threadIdx.x < H1_F) sb1[threadIdx.x] = b1[threadIdx.x];
    if (threadIdx.x < H2_F) sb2[threadIdx.x] = b2[threadIdx.x];
    __syncthreads();

    long long gid = (long long)blockIdx.x * 256 + threadIdx.x;
    if (gid >= (long long)B_SZ * E) return;
    int e = (int)(gid >> 2);
    int b = (int)(gid & 3);
    int src = ei[e];
    int tgt = ei[E + e];
    float s1 = sums[0], s2 = sums[1];
    float mean = s1 / (float)E;
    float var = (s2 - (float)E * mean * mean) / (float)(E - 1);
    float eav = (ea[e] - mean) * rsqrtf(var);
    float h1[H1_F];
#pragma unroll
    for (int j = 0; j < H1_F; j++) h1[j] = sb1[j] + eav * sW1[2 * IN_F * H1_F + j];
    const float4* xs4 = (const float4*)(x + ((size_t)b * N + src) * IN_F);
    const float4* xt4 = (const float4*)(x + ((size_t)b * N + tgt) * IN_F);
#pragma unroll
    for (int i4 = 0; i4 < IN_F / 4; i4++) {
        float4 a = xs4[i4];
        float4 c = xt4[i4];
        const float* w_s = &sW1[(i4 * 4) * H1_F];
        const float* w_t = &sW1[(IN_F + i4 * 4) * H1_F];
#pragma unroll
        for (int j = 0; j < H1_F; j++) {
            h1[j] += a.x * w_s[j] + a.y * w_s[H1_F + j] + a.z * w_s[2 * H1_F + j]
                   + a.w * w_s[3 * H1_F + j] + c.x * w_t[j] + c.y * w_t[H1_F + j]
                   + c.z * w_t[2 * H1_F + j] + c.w * w_t[3 * H1_F + j];
        }
    }
#pragma unroll
    for (int i = 0; i < H1_F; i++) h1[i] = sigmoidf_(h1[i]);
    float h2[H2_F];
#pragma unroll
    for (int j = 0; j < H2_F; j++) h2[j] = sb2[j];
#pragma unroll
    for (int i = 0; i < H1_F; i++) {
        float a = h1[i];
#pragma unroll
        for (int j = 0; j < H2_F; j++) h2[j] += a * sW2[i * H2_F + j];
    }
    float* at = acc + ((size_t)b * N + tgt) * H2_F;
    float* as = acc + ((size_t)b * N + src) * H2_F;
#pragma unroll
    for (int j = 0; j < H2_F; j++) {
        float hv = sigmoidf_(h2[j]);
        unsafeAtomicAdd(at + j, hv);
        unsafeAtomicAdd(as + j, -hv);
    }
}

__global__ void __launch_bounds__(256) final_kernel(const float* __restrict__ acc,
                                                    const float* __restrict__ W3,
                                                    const float* __restrict__ b3,
                                                    float* __restrict__ out, int BN) {
    __shared__ float sW3[H2_F * 32];
    __shared__ float sb3[32];
    __shared__ float srow[8][H2_F];
    for (int i = threadIdx.x; i < H2_F * 32; i += 256) sW3[i] = W3[i];
    if (threadIdx.x < 32) sb3[threadIdx.x] = b3[threadIdx.x];
    int row0 = blockIdx.x * 8;
    for (int i = threadIdx.x; i < 8 * H2_F; i += 256) {
        int r = i / H2_F, k = i % H2_F;
        int rr = row0 + r;
        srow[r][k] = (rr < BN) ? acc[(size_t)rr * H2_F + k] : 0.f;
    }
    __syncthreads();
    int r = threadIdx.x >> 5;
    int j = threadIdx.x & 31;
    int row = row0 + r;
    if (row < BN) {
        float a = sb3[j];
#pragma unroll
        for (int k = 0; k < H2_F; k++) a += srow[r][k] * sW3[k * 32 + j];
        out[(size_t)row * 32 + j] = sigmoidf_(a);
    }
}

// ---------------------------------------------------------------------------
extern "C" void kernel_launch(void* const* d_in, const int* in_sizes, int n_in,
                              void* d_out, int out_size, void* d_ws, size_t ws_size,
                              hipStream_t stream) {
    const float* x  = (const float*)d_in[0];
    const int*   ei = (const int*)d_in[1];
    const float* ea = (const float*)d_in[2];
    const float* W1 = (const float*)d_in[3];
    const float* b1 = (const float*)d_in[4];
    const float* W2 = (const float*)d_in[5];
    const float* b2 = (const float*)d_in[6];
    const float* W3 = (const float*)d_in[7];
    const float* b3 = (const float*)d_in[8];
    float* out = (float*)d_out;

    const int E  = in_sizes[2];
    const int N  = in_sizes[0] / (B_SZ * IN_F);
    const int BN = B_SZ * N;

    // CSR-path workspace layout
    size_t hBytes = (size_t)E * B_SZ * H2_F * sizeof(ushort);  // bf16 h
    ushort* h   = (ushort*)d_ws;
    int* cnt    = (int*)((char*)d_ws + hBytes);
    int* offs   = cnt + 2 * (size_t)N;
    int* cursor = offs + 2 * (size_t)N + 1;
    int* list   = cursor + 2 * (size_t)N;
    float* sums = (float*)(list + 2 * (size_t)E);
    size_t need = hBytes + ((size_t)6 * N + 1 + 2 * (size_t)E) * 4 + 8;

    if (ws_size >= need) {
        hipMemsetAsync(cnt, 0, 2 * (size_t)N * sizeof(int), stream);
        hipMemsetAsync(sums, 0, 2 * sizeof(float), stream);

        stats_kernel<<<256, 256, 0, stream>>>(ea, sums, E);
        hist_kernel<<<(E + 255) / 256, 256, 0, stream>>>(ei, cnt, E, N);
        scan_kernel<<<1, 1024, 0, stream>>>(cnt, offs, cursor, 2 * N);

        long long total = (long long)B_SZ * E;
        int blocks = (int)((total + 255) / 256);
        edge_mlp_kernel<<<blocks, 256, 0, stream>>>(x, ei, ea, W1, b1, W2, b2,
                                                    sums, h, E, N);
        scatter_kernel<<<(E + 255) / 256, 256, 0, stream>>>(ei, cursor, list, E, N);
        gather_final_kernel<<<(N + 1) / 2, 256, 0, stream>>>(h, list, offs, W3, b3,
                                                             out, N);
    } else {
        // fallback: round-1 atomic path (needs 24 MB)
        float* acc   = (float*)d_ws;
        float* sumsF = acc + (size_t)BN * H2_F;
        hipMemsetAsync(d_ws, 0,
                       (size_t)BN * H2_F * sizeof(float) + 2 * sizeof(float), stream);
        stats_kernel<<<256, 256, 0, stream>>>(ea, sumsF, E);
        long long total = (long long)B_SZ * E;
        int blocks = (int)((total + 255) / 256);
        edge_kernel_atomic<<<blocks, 256, 0, stream>>>(x, ei, ea, W1, b1, W2, b2,
                                                       sumsF, acc, E, N);
        final_kernel<<<(BN + 7) / 8, 256, 0, stream>>>(acc, W3, b3, out, BN);
    }
}

// Round 3
// 584.978 us; speedup vs baseline: 16.5896x; 2.1425x over previous
//
#include <hip/hip_runtime.h>
#include <math.h>

#define B_SZ 4
#define IN_F 32
#define H1_F 32
#define H2_F 30
#define TPW 16   // row-tiles per wave in edge kernel

typedef unsigned int uint;
typedef unsigned short ushort;
typedef __attribute__((ext_vector_type(8))) short bf16x8;
typedef __attribute__((ext_vector_type(4))) float f32x4;

__device__ __forceinline__ float sigmoidf_(float x) { return 1.f / (1.f + __expf(-x)); }

__device__ __forceinline__ ushort f2bf(float f) {
    uint u = __float_as_uint(f);
    return (ushort)((u + 0x7FFFu + ((u >> 16) & 1u)) >> 16);  // RNE
}
__device__ __forceinline__ float bf2f(ushort v) { return __uint_as_float(((uint)v) << 16); }
__device__ __forceinline__ uint pk2(float a, float b) {
    return (uint)f2bf(a) | ((uint)f2bf(b) << 16);
}

union Frag { bf16x8 v; ushort us[8]; uint u[4]; };

// ---------------------------------------------------------------------------
// stats: mean / sumsq of edge_attr
// ---------------------------------------------------------------------------
__global__ void __launch_bounds__(256) stats_kernel(const float* __restrict__ ea,
                                                    float* __restrict__ sums, int E) {
    int gid = blockIdx.x * blockDim.x + threadIdx.x;
    int stride = gridDim.x * blockDim.x;
    float v = 0.f, v2 = 0.f;
    for (int i = gid; i < E; i += stride) {
        float a = ea[i];
        v += a; v2 += a * a;
    }
    for (int off = 32; off > 0; off >>= 1) {
        v  += __shfl_down(v, off);
        v2 += __shfl_down(v2, off);
    }
    __shared__ float s1[4], s2[4];
    int wid = threadIdx.x >> 6, lane = threadIdx.x & 63;
    if (lane == 0) { s1[wid] = v; s2[wid] = v2; }
    __syncthreads();
    if (threadIdx.x == 0) {
        unsafeAtomicAdd(&sums[0], s1[0] + s1[1] + s1[2] + s1[3]);
        unsafeAtomicAdd(&sums[1], s2[0] + s2[1] + s2[2] + s2[3]);
    }
}

// ---------------------------------------------------------------------------
// hist: combined degree (tgt + src) per node
// ---------------------------------------------------------------------------
__global__ void __launch_bounds__(256) hist_kernel(const int* __restrict__ ei,
                                                   int* __restrict__ cnt, int E, int N) {
    int e = blockIdx.x * 256 + threadIdx.x;
    if (e < E) {
        atomicAdd(&cnt[ei[E + e]], 1);
        atomicAdd(&cnt[ei[e]], 1);
    }
}

// ---------------------------------------------------------------------------
// 3-phase multi-block exclusive scan (1024 elems/block)
// ---------------------------------------------------------------------------
__global__ void __launch_bounds__(256) scan1_kernel(const int* __restrict__ cnt,
                                                    int* __restrict__ offs,
                                                    int* __restrict__ bsum, int n) {
    __shared__ int wtot[4];
    int base = blockIdx.x * 1024 + threadIdx.x * 4;
    int4 v = {0, 0, 0, 0};
    if (base + 3 < n) v = *(const int4*)(cnt + base);
    else {
        if (base < n)     v.x = cnt[base];
        if (base + 1 < n) v.y = cnt[base + 1];
        if (base + 2 < n) v.z = cnt[base + 2];
        if (base + 3 < n) v.w = cnt[base + 3];
    }
    int s = v.x + v.y + v.z + v.w;
    int incl = s;
    int lane = threadIdx.x & 63;
    for (int d = 1; d < 64; d <<= 1) {
        int t = __shfl_up(incl, d);
        if (lane >= d) incl += t;
    }
    int wid = threadIdx.x >> 6;
    if (lane == 63) wtot[wid] = incl;
    __syncthreads();
    int woff = 0, tot = 0;
#pragma unroll
    for (int w = 0; w < 4; w++) {
        int t = wtot[w];
        if (w < wid) woff += t;
        tot += t;
    }
    int excl = woff + incl - s;
    int4 o;
    o.x = excl; o.y = excl + v.x; o.z = o.y + v.y; o.w = o.z + v.z;
    if (base + 3 < n) *(int4*)(offs + base) = o;
    else {
        if (base < n)     offs[base] = o.x;
        if (base + 1 < n) offs[base + 1] = o.y;
        if (base + 2 < n) offs[base + 2] = o.z;
        if (base + 3 < n) offs[base + 3] = o.w;
    }
    if (threadIdx.x == 0) bsum[blockIdx.x] = tot;
}

__global__ void scan2_kernel(int* __restrict__ bsum, int* __restrict__ offs,
                             int nb, int n) {
    int lane = threadIdx.x;
    if (nb <= 64) {
        int v = (lane < nb) ? bsum[lane] : 0;
        int incl = v;
        for (int d = 1; d < 64; d <<= 1) {
            int t = __shfl_up(incl, d);
            if (lane >= d) incl += t;
        }
        if (lane < nb) bsum[lane] = incl - v;
        if (lane == 63) offs[n] = incl;
    } else if (lane == 0) {
        int run = 0;
        for (int i = 0; i < nb; i++) { int t = bsum[i]; bsum[i] = run; run += t; }
        offs[n] = run;
    }
}

__global__ void __launch_bounds__(256) scan3_kernel(int* __restrict__ offs,
                                                    int* __restrict__ cursor,
                                                    const int* __restrict__ bsum, int n) {
    int base = blockIdx.x * 1024 + threadIdx.x * 4;
    int add = bsum[blockIdx.x];
    if (base + 3 < n) {
        int4 v = *(const int4*)(offs + base);
        v.x += add; v.y += add; v.z += add; v.w += add;
        *(int4*)(offs + base) = v;
        *(int4*)(cursor + base) = v;
    } else {
        for (int k = 0; k < 4; k++) {
            int i = base + k;
            if (i < n) { int v = offs[i] + add; offs[i] = v; cursor[i] = v; }
        }
    }
}

// ---------------------------------------------------------------------------
// scatter: signed combined adjacency list (sign bit = src side)
// ---------------------------------------------------------------------------
__global__ void __launch_bounds__(256) scatter_kernel(const int* __restrict__ ei,
                                                      int* __restrict__ cursor,
                                                      int* __restrict__ list, int E, int N) {
    int e = blockIdx.x * 256 + threadIdx.x;
    if (e < E) {
        int tgt = ei[E + e];
        int p = atomicAdd(&cursor[tgt], 1);
        list[p] = e;                                // '+' contribution
        int src = ei[e];
        int q = atomicAdd(&cursor[src], 1);
        list[q] = e | (int)0x80000000u;             // '-' contribution
    }
}

// ---------------------------------------------------------------------------
// edge MLP via MFMA. 16-row tiles: row = e_local*4 + b (4 edges x 4 batches).
// h output layout: [e][b][30] bf16 (dense 240 B per edge).
// ---------------------------------------------------------------------------
__global__ void __launch_bounds__(256) edge_mlp_mfma(
    const float* __restrict__ x, const int* __restrict__ ei,
    const float* __restrict__ ea,
    const float* __restrict__ W1, const float* __restrict__ b1,
    const float* __restrict__ W2, const float* __restrict__ b2,
    const float* __restrict__ sums, ushort* __restrict__ h,
    int E, int N, int tiles) {
    // per-wave LDS: buf1 = h1 bounce (stride 40 for bank spread + 16B align),
    //               buf2 = h2 store staging (dense stride 30)
    __shared__ ushort __attribute__((aligned(16))) buf1[4][16 * 40];
    __shared__ ushort __attribute__((aligned(16))) buf2[4][16 * 30];
    int w = threadIdx.x >> 6;
    int lane = threadIdx.x & 63;
    int n16 = lane & 15;
    int quad = lane >> 4;

    // ---- preload weight B-fragments into registers (B[k][n]: n=lane&15, k=quad*8+j)
    Frag w1f[2][2];
    float w1L[2], b1f[2];
#pragma unroll
    for (int t = 0; t < 2; t++) {
#pragma unroll
        for (int s = 0; s < 2; s++) {
#pragma unroll
            for (int j = 0; j < 4; j++) {
                int k0 = 32 * s + quad * 8 + 2 * j;
                float a = W1[(size_t)k0 * 32 + 16 * t + n16];
                float c = W1[(size_t)(k0 + 1) * 32 + 16 * t + n16];
                w1f[t][s].u[j] = pk2(a, c);
            }
        }
        w1L[t] = W1[(size_t)64 * 32 + 16 * t + n16];
        b1f[t] = b1[16 * t + n16];
    }
    Frag w2f[2];
    float b2f[2];
#pragma unroll
    for (int t = 0; t < 2; t++) {
        int c = 16 * t + n16;
#pragma unroll
        for (int j = 0; j < 4; j++) {
            int k0 = quad * 8 + 2 * j;
            float a = (c < H2_F) ? W2[(size_t)k0 * H2_F + c] : 0.f;
            float d = (c < H2_F) ? W2[(size_t)(k0 + 1) * H2_F + c] : 0.f;
            w2f[t].u[j] = pk2(a, d);
        }
        b2f[t] = (c < H2_F) ? b2[c] : 0.f;
    }

    float mean = sums[0] / (float)E;
    float var = (sums[1] - (float)E * mean * mean) / (float)(E - 1);
    float istd = rsqrtf(var);

    int m = n16;          // A-operand row for this lane
    int b = m & 3;        // batch of A-row
    int eAoff = m >> 2;   // edge offset of A-row within tile
    int gw = blockIdx.x * 4 + w;

    for (int tix = 0; tix < TPW; ++tix) {
        int tile = gw * TPW + tix;
        if (tile >= tiles) break;
        int e0 = tile * 4;
        int eA = e0 + eAoff; if (eA >= E) eA = E - 1;
        int eC = e0 + quad;  if (eC >= E) eC = E - 1;
        int src = ei[eA], tgt = ei[E + eA];
        float eav = (ea[eC] - mean) * istd;

        // A-fragments direct from global (8 contiguous floats -> bf16x8)
        const float4* ps = (const float4*)(x + ((size_t)b * N + src) * IN_F + quad * 8);
        float4 s0 = ps[0], s1 = ps[1];
        const float4* pt = (const float4*)(x + ((size_t)b * N + tgt) * IN_F + quad * 8);
        float4 t0 = pt[0], t1 = pt[1];
        Frag a0, a1;
        a0.u[0] = pk2(s0.x, s0.y); a0.u[1] = pk2(s0.z, s0.w);
        a0.u[2] = pk2(s1.x, s1.y); a0.u[3] = pk2(s1.z, s1.w);
        a1.u[0] = pk2(t0.x, t0.y); a1.u[1] = pk2(t0.z, t0.w);
        a1.u[2] = pk2(t1.x, t1.y); a1.u[3] = pk2(t1.z, t1.w);

        // layer 1: init = b1 + eav*W1[64]  (C-rows of this lane share one edge)
        float i0 = b1f[0] + eav * w1L[0];
        float i1 = b1f[1] + eav * w1L[1];
        f32x4 acc0, acc1;
        acc0[0] = i0; acc0[1] = i0; acc0[2] = i0; acc0[3] = i0;
        acc1[0] = i1; acc1[1] = i1; acc1[2] = i1; acc1[3] = i1;
        acc0 = __builtin_amdgcn_mfma_f32_16x16x32_bf16(a0.v, w1f[0][0].v, acc0, 0, 0, 0);
        acc0 = __builtin_amdgcn_mfma_f32_16x16x32_bf16(a1.v, w1f[0][1].v, acc0, 0, 0, 0);
        acc1 = __builtin_amdgcn_mfma_f32_16x16x32_bf16(a0.v, w1f[1][0].v, acc1, 0, 0, 0);
        acc1 = __builtin_amdgcn_mfma_f32_16x16x32_bf16(a1.v, w1f[1][1].v, acc1, 0, 0, 0);

        // sigmoid -> LDS (C-layout write), wave-synchronous
#pragma unroll
        for (int r = 0; r < 4; r++) {
            int row = quad * 4 + r;
            buf1[w][row * 40 + n16]      = f2bf(sigmoidf_(acc0[r]));
            buf1[w][row * 40 + 16 + n16] = f2bf(sigmoidf_(acc1[r]));
        }
        // layer-2 A-fragment: h1[m][quad*8 + j]
        Frag ha;
        *(uint4*)&ha.u[0] = *(const uint4*)&buf1[w][m * 40 + quad * 8];

        f32x4 c0, c1;
        c0[0] = b2f[0]; c0[1] = b2f[0]; c0[2] = b2f[0]; c0[3] = b2f[0];
        c1[0] = b2f[1]; c1[1] = b2f[1]; c1[2] = b2f[1]; c1[3] = b2f[1];
        c0 = __builtin_amdgcn_mfma_f32_16x16x32_bf16(ha.v, w2f[0].v, c0, 0, 0, 0);
        c1 = __builtin_amdgcn_mfma_f32_16x16x32_bf16(ha.v, w2f[1].v, c1, 0, 0, 0);

        // sigmoid -> dense staging buffer [row][30]
#pragma unroll
        for (int r = 0; r < 4; r++) {
            int row = quad * 4 + r;
            buf2[w][row * 30 + n16] = f2bf(sigmoidf_(c0[r]));
            if (n16 < H2_F - 16)
                buf2[w][row * 30 + 16 + n16] = f2bf(sigmoidf_(c1[r]));
        }
        // cooperative coalesced store: ne edges * 240 B contiguous
        int ne = E - e0; if (ne > 4) ne = 4;
        int ndw = ne * 60;
        const uint* sbuf = (const uint*)&buf2[w][0];
        uint* gdst = (uint*)(h + (size_t)e0 * 120);
        for (int i = lane; i < ndw; i += 64) gdst[i] = sbuf[i];
    }
}

// ---------------------------------------------------------------------------
// gather + fused W3: one wave per node; signed combined list
// ---------------------------------------------------------------------------
__global__ void __launch_bounds__(256) gather_final(
    const ushort* __restrict__ h, const int* __restrict__ list,
    const int* __restrict__ offs, const float* __restrict__ W3,
    const float* __restrict__ b3, float* __restrict__ out, int N) {
    __shared__ float sW3[H2_F * 32];
    __shared__ float sb3[32];
    __shared__ float sacc[4][B_SZ][H2_F];
    for (int i = threadIdx.x; i < H2_F * 32; i += 256) sW3[i] = W3[i];
    if (threadIdx.x < 32) sb3[threadIdx.x] = b3[threadIdx.x];
    __syncthreads();

    int w = threadIdx.x >> 6, lane = threadIdx.x & 63;
    int n = blockIdx.x * 4 + w;
    if (n >= N) return;

    if (lane < 60) {
        int bq = lane / 15, jp = lane % 15;   // this lane covers cols 2jp, 2jp+1 of batch bq
        float a0 = 0.f, a1 = 0.f;
        int s = offs[n], e = offs[n + 1];
        int i = s;
        for (; i + 4 <= e; i += 4) {
            int v0 = list[i], v1 = list[i + 1], v2 = list[i + 2], v3 = list[i + 3];
            uint d0 = *(const uint*)(h + (size_t)(v0 & 0x7FFFFFFF) * 120 + bq * 30 + jp * 2);
            uint d1 = *(const uint*)(h + (size_t)(v1 & 0x7FFFFFFF) * 120 + bq * 30 + jp * 2);
            uint d2 = *(const uint*)(h + (size_t)(v2 & 0x7FFFFFFF) * 120 + bq * 30 + jp * 2);
            uint d3 = *(const uint*)(h + (size_t)(v3 & 0x7FFFFFFF) * 120 + bq * 30 + jp * 2);
            float g0 = (v0 < 0) ? -1.f : 1.f;
            float g1 = (v1 < 0) ? -1.f : 1.f;
            float g2 = (v2 < 0) ? -1.f : 1.f;
            float g3 = (v3 < 0) ? -1.f : 1.f;
            a0 += g0 * bf2f((ushort)d0) + g1 * bf2f((ushort)d1)
                + g2 * bf2f((ushort)d2) + g3 * bf2f((ushort)d3);
            a1 += g0 * bf2f((ushort)(d0 >> 16)) + g1 * bf2f((ushort)(d1 >> 16))
                + g2 * bf2f((ushort)(d2 >> 16)) + g3 * bf2f((ushort)(d3 >> 16));
        }
        for (; i < e; i++) {
            int v = list[i];
            uint d = *(const uint*)(h + (size_t)(v & 0x7FFFFFFF) * 120 + bq * 30 + jp * 2);
            float g = (v < 0) ? -1.f : 1.f;
            a0 += g * bf2f((ushort)d);
            a1 += g * bf2f((ushort)(d >> 16));
        }
        sacc[w][bq][jp * 2]     = a0;
        sacc[w][bq][jp * 2 + 1] = a1;
    }
    // wave-synchronous: epilogue reads this wave's sacc slice
    int b = lane >> 4, k = lane & 15;
    float o0 = sb3[k], o1 = sb3[k + 16];
#pragma unroll
    for (int j = 0; j < H2_F; j++) {
        float v = sacc[w][b][j];
        o0 += v * sW3[j * 32 + k];
        o1 += v * sW3[j * 32 + k + 16];
    }
    float* op = out + ((size_t)b * N + n) * 32;
    op[k]      = sigmoidf_(o0);
    op[k + 16] = sigmoidf_(o1);
}

// ---------------------------------------------------------------------------
// fallback (small ws): round-1 atomic path
// ---------------------------------------------------------------------------
__global__ void __launch_bounds__(256) edge_kernel_atomic(
    const float* __restrict__ x, const int* __restrict__ ei,
    const float* __restrict__ ea,
    const float* __restrict__ W1, const float* __restrict__ b1,
    const float* __restrict__ W2, const float* __restrict__ b2,
    const float* __restrict__ sums, float* __restrict__ acc, int E, int N) {
    __shared__ float sW1[(2 * IN_F + 1) * H1_F];
    __shared__ float sb1[H1_F];
    __shared__ float sW2[H1_F * H2_F];
    __shared__ float sb2[H2_F];
    for (int i = threadIdx.x; i < (2 * IN_F + 1) * H1_F; i += 256) sW1[i] = W1[i];
    for (int i = threadIdx.x; i < H1_F * H2_F; i += 256) sW2[i] = W2[i];
    if (threadIdx.x < H1_F) sb1[threadIdx.x] = b1[threadIdx.x];
    if (threadIdx.x < H2_F) sb2[threadIdx.x] = b2[threadIdx.x];
    __syncthreads();
    long long gid = (long long)blockIdx.x * 256 + threadIdx.x;
    if (gid >= (long long)B_SZ * E) return;
    int e = (int)(gid >> 2);
    int b = (int)(gid & 3);
    int src = ei[e];
    int tgt = ei[E + e];
    float s1 = sums[0], s2 = sums[1];
    float mean = s1 / (float)E;
    float var = (s2 - (float)E * mean * mean) / (float)(E - 1);
    float eav = (ea[e] - mean) * rsqrtf(var);
    float h1[H1_F];
#pragma unroll
    for (int j = 0; j < H1_F; j++) h1[j] = sb1[j] + eav * sW1[2 * IN_F * H1_F + j];
    const float4* xs4 = (const float4*)(x + ((size_t)b * N + src) * IN_F);
    const float4* xt4 = (const float4*)(x + ((size_t)b * N + tgt) * IN_F);
#pragma unroll
    for (int i4 = 0; i4 < IN_F / 4; i4++) {
        float4 a = xs4[i4];
        float4 c = xt4[i4];
        const float* w_s = &sW1[(i4 * 4) * H1_F];
        const float* w_t = &sW1[(IN_F + i4 * 4) * H1_F];
#pragma unroll
        for (int j = 0; j < H1_F; j++) {
            h1[j] += a.x * w_s[j] + a.y * w_s[H1_F + j] + a.z * w_s[2 * H1_F + j]
                   + a.w * w_s[3 * H1_F + j] + c.x * w_t[j] + c.y * w_t[H1_F + j]
                   + c.z * w_t[2 * H1_F + j] + c.w * w_t[3 * H1_F + j];
        }
    }
#pragma unroll
    for (int i = 0; i < H1_F; i++) h1[i] = sigmoidf_(h1[i]);
    float h2[H2_F];
#pragma unroll
    for (int j = 0; j < H2_F; j++) h2[j] = sb2[j];
#pragma unroll
    for (int i = 0; i < H1_F; i++) {
        float a = h1[i];
#pragma unroll
        for (int j = 0; j < H2_F; j++) h2[j] += a * sW2[i * H2_F + j];
    }
    float* at = acc + ((size_t)b * N + tgt) * H2_F;
    float* as = acc + ((size_t)b * N + src) * H2_F;
#pragma unroll
    for (int j = 0; j < H2_F; j++) {
        float hv = sigmoidf_(h2[j]);
        unsafeAtomicAdd(at + j, hv);
        unsafeAtomicAdd(as + j, -hv);
    }
}

__global__ void __launch_bounds__(256) final_kernel(const float* __restrict__ acc,
                                                    const float* __restrict__ W3,
                                                    const float* __restrict__ b3,
                                                    float* __restrict__ out, int BN) {
    __shared__ float sW3[H2_F * 32];
    __shared__ float sb3[32];
    __shared__ float srow[8][H2_F];
    for (int i = threadIdx.x; i < H2_F * 32; i += 256) sW3[i] = W3[i];
    if (threadIdx.x < 32) sb3[threadIdx.x] = b3[threadIdx.x];
    int row0 = blockIdx.x * 8;
    for (int i = threadIdx.x; i < 8 * H2_F; i += 256) {
        int r = i / H2_F, k = i % H2_F;
        int rr = row0 + r;
        srow[r][k] = (rr < BN) ? acc[(size_t)rr * H2_F + k] : 0.f;
    }
    __syncthreads();
    int r = threadIdx.x >> 5;
    int j = threadIdx.x & 31;
    int row = row0 + r;
    if (row < BN) {
        float a = sb3[j];
#pragma unroll
        for (int k = 0; k < H2_F; k++) a += srow[r][k] * sW3[k * 32 + j];
        out[(size_t)row * 32 + j] = sigmoidf_(a);
    }
}

// ---------------------------------------------------------------------------
extern "C" void kernel_launch(void* const* d_in, const int* in_sizes, int n_in,
                              void* d_out, int out_size, void* d_ws, size_t ws_size,
                              hipStream_t stream) {
    const float* x  = (const float*)d_in[0];
    const int*   ei = (const int*)d_in[1];
    const float* ea = (const float*)d_in[2];
    const float* W1 = (const float*)d_in[3];
    const float* b1 = (const float*)d_in[4];
    const float* W2 = (const float*)d_in[5];
    const float* b2 = (const float*)d_in[6];
    const float* W3 = (const float*)d_in[7];
    const float* b3 = (const float*)d_in[8];
    float* out = (float*)d_out;

    const int E  = in_sizes[2];
    const int N  = in_sizes[0] / (B_SZ * IN_F);
    const int BN = B_SZ * N;

    // ws layout: h [E*4*30 bf16] | list [2E] | cnt [N] | offs [N+1] | cursor [N]
    //            | bsum [1024] | sums [2]
    ushort* h   = (ushort*)d_ws;
    int* list   = (int*)((char*)d_ws + (size_t)E * 120 * sizeof(ushort));
    int* cnt    = list + 2 * (size_t)E;
    int* offs   = cnt + N;
    int* cursor = offs + N + 1;
    int* bsum   = cursor + N;
    float* sums = (float*)(bsum + 1024);
    size_t need = (size_t)((char*)(sums + 2) - (char*)d_ws);

    if (ws_size >= need) {
        hipMemsetAsync(cnt, 0, (size_t)N * sizeof(int), stream);
        hipMemsetAsync(sums, 0, 2 * sizeof(float), stream);

        stats_kernel<<<256, 256, 0, stream>>>(ea, sums, E);
        hist_kernel<<<(E + 255) / 256, 256, 0, stream>>>(ei, cnt, E, N);
        int nb = (N + 1023) / 1024;
        scan1_kernel<<<nb, 256, 0, stream>>>(cnt, offs, bsum, N);
        scan2_kernel<<<1, 64, 0, stream>>>(bsum, offs, nb, N);
        scan3_kernel<<<nb, 256, 0, stream>>>(offs, cursor, bsum, N);
        scatter_kernel<<<(E + 255) / 256, 256, 0, stream>>>(ei, cursor, list, E, N);

        int tiles = (E + 3) / 4;
        int waves = (tiles + TPW - 1) / TPW;
        int blocks = (waves + 3) / 4;
        edge_mlp_mfma<<<blocks, 256, 0, stream>>>(x, ei, ea, W1, b1, W2, b2,
                                                  sums, h, E, N, tiles);
        gather_final<<<(N + 3) / 4, 256, 0, stream>>>(h, list, offs, W3, b3, out, N);
    } else {
        float* acc   = (float*)d_ws;
        float* sumsF = acc + (size_t)BN * H2_F;
        hipMemsetAsync(d_ws, 0,
                       (size_t)BN * H2_F * sizeof(float) + 2 * sizeof(float), stream);
        stats_kernel<<<256, 256, 0, stream>>>(ea, sumsF, E);
        long long total = (long long)B_SZ * E;
        int blocks = (int)((total + 255) / 256);
        edge_kernel_atomic<<<blocks, 256, 0, stream>>>(x, ei, ea, W1, b1, W2, b2,
                                                       sumsF, acc, E, N);
        final_kernel<<<(BN + 7) / 8, 256, 0, stream>>>(acc, W3, b3, out, BN);
    }
}

// Round 4
// 582.811 us; speedup vs baseline: 16.6513x; 1.0037x over previous
//
#include <hip/hip_runtime.h>
#include <math.h>

#define B_SZ 4
#define IN_F 32
#define H1_F 32
#define H2_F 30
#define TPW 16   // row-tiles per wave in edge kernel

typedef unsigned int uint;
typedef unsigned short ushort;
typedef __attribute__((ext_vector_type(8))) short bf16x8;
typedef __attribute__((ext_vector_type(4))) float f32x4;

__device__ __forceinline__ float sigmoidf_(float x) { return 1.f / (1.f + __expf(-x)); }

__device__ __forceinline__ ushort f2bf(float f) {
    uint u = __float_as_uint(f);
    return (ushort)((u + 0x7FFFu + ((u >> 16) & 1u)) >> 16);  // RNE
}
__device__ __forceinline__ float bf2f(ushort v) { return __uint_as_float(((uint)v) << 16); }
__device__ __forceinline__ uint pk2(float a, float b) {
    return (uint)f2bf(a) | ((uint)f2bf(b) << 16);
}

union Frag { bf16x8 v; ushort us[8]; uint u[4]; };

// ---------------------------------------------------------------------------
// stats: mean / sumsq of edge_attr
// ---------------------------------------------------------------------------
__global__ void __launch_bounds__(256) stats_kernel(const float* __restrict__ ea,
                                                    float* __restrict__ sums, int E) {
    int gid = blockIdx.x * blockDim.x + threadIdx.x;
    int stride = gridDim.x * blockDim.x;
    float v = 0.f, v2 = 0.f;
    for (int i = gid; i < E; i += stride) {
        float a = ea[i];
        v += a; v2 += a * a;
    }
    for (int off = 32; off > 0; off >>= 1) {
        v  += __shfl_down(v, off);
        v2 += __shfl_down(v2, off);
    }
    __shared__ float s1[4], s2[4];
    int wid = threadIdx.x >> 6, lane = threadIdx.x & 63;
    if (lane == 0) { s1[wid] = v; s2[wid] = v2; }
    __syncthreads();
    if (threadIdx.x == 0) {
        unsafeAtomicAdd(&sums[0], s1[0] + s1[1] + s1[2] + s1[3]);
        unsafeAtomicAdd(&sums[1], s2[0] + s2[1] + s2[2] + s2[3]);
    }
}

// ---------------------------------------------------------------------------
// x f32 -> bf16 conversion (8 elems/thread)
// ---------------------------------------------------------------------------
__global__ void __launch_bounds__(256) xcvt_kernel(const float* __restrict__ x,
                                                   ushort* __restrict__ xb,
                                                   long long n8) {
    long long i = (long long)blockIdx.x * 256 + threadIdx.x;
    if (i >= n8) return;
    const float4* p = (const float4*)(x + i * 8);
    float4 v0 = p[0], v1 = p[1];
    uint4 o;
    o.x = pk2(v0.x, v0.y); o.y = pk2(v0.z, v0.w);
    o.z = pk2(v1.x, v1.y); o.w = pk2(v1.z, v1.w);
    *(uint4*)(xb + i * 8) = o;
}

// ---------------------------------------------------------------------------
// hist: combined degree (tgt + src) per node
// ---------------------------------------------------------------------------
__global__ void __launch_bounds__(256) hist_kernel(const int* __restrict__ ei,
                                                   int* __restrict__ cnt, int E, int N) {
    int e = blockIdx.x * 256 + threadIdx.x;
    if (e < E) {
        atomicAdd(&cnt[ei[E + e]], 1);
        atomicAdd(&cnt[ei[e]], 1);
    }
}

// ---------------------------------------------------------------------------
// 3-phase multi-block exclusive scan (1024 elems/block)
// ---------------------------------------------------------------------------
__global__ void __launch_bounds__(256) scan1_kernel(const int* __restrict__ cnt,
                                                    int* __restrict__ offs,
                                                    int* __restrict__ bsum, int n) {
    __shared__ int wtot[4];
    int base = blockIdx.x * 1024 + threadIdx.x * 4;
    int4 v = {0, 0, 0, 0};
    if (base + 3 < n) v = *(const int4*)(cnt + base);
    else {
        if (base < n)     v.x = cnt[base];
        if (base + 1 < n) v.y = cnt[base + 1];
        if (base + 2 < n) v.z = cnt[base + 2];
        if (base + 3 < n) v.w = cnt[base + 3];
    }
    int s = v.x + v.y + v.z + v.w;
    int incl = s;
    int lane = threadIdx.x & 63;
    for (int d = 1; d < 64; d <<= 1) {
        int t = __shfl_up(incl, d);
        if (lane >= d) incl += t;
    }
    int wid = threadIdx.x >> 6;
    if (lane == 63) wtot[wid] = incl;
    __syncthreads();
    int woff = 0, tot = 0;
#pragma unroll
    for (int w = 0; w < 4; w++) {
        int t = wtot[w];
        if (w < wid) woff += t;
        tot += t;
    }
    int excl = woff + incl - s;
    int4 o;
    o.x = excl; o.y = excl + v.x; o.z = o.y + v.y; o.w = o.z + v.z;
    if (base + 3 < n) *(int4*)(offs + base) = o;
    else {
        if (base < n)     offs[base] = o.x;
        if (base + 1 < n) offs[base + 1] = o.y;
        if (base + 2 < n) offs[base + 2] = o.z;
        if (base + 3 < n) offs[base + 3] = o.w;
    }
    if (threadIdx.x == 0) bsum[blockIdx.x] = tot;
}

__global__ void scan2_kernel(int* __restrict__ bsum, int* __restrict__ offs,
                             int nb, int n) {
    int lane = threadIdx.x;
    if (nb <= 64) {
        int v = (lane < nb) ? bsum[lane] : 0;
        int incl = v;
        for (int d = 1; d < 64; d <<= 1) {
            int t = __shfl_up(incl, d);
            if (lane >= d) incl += t;
        }
        if (lane < nb) bsum[lane] = incl - v;
        if (lane == 63) offs[n] = incl;
    } else if (lane == 0) {
        int run = 0;
        for (int i = 0; i < nb; i++) { int t = bsum[i]; bsum[i] = run; run += t; }
        offs[n] = run;
    }
}

__global__ void __launch_bounds__(256) scan3_kernel(int* __restrict__ offs,
                                                    int* __restrict__ cursor,
                                                    const int* __restrict__ bsum, int n) {
    int base = blockIdx.x * 1024 + threadIdx.x * 4;
    int add = bsum[blockIdx.x];
    if (base + 3 < n) {
        int4 v = *(const int4*)(offs + base);
        v.x += add; v.y += add; v.z += add; v.w += add;
        *(int4*)(offs + base) = v;
        *(int4*)(cursor + base) = v;
    } else {
        for (int k = 0; k < 4; k++) {
            int i = base + k;
            if (i < n) { int v = offs[i] + add; offs[i] = v; cursor[i] = v; }
        }
    }
}

// ---------------------------------------------------------------------------
// scatter: signed combined adjacency list (sign bit = src side)
// ---------------------------------------------------------------------------
__global__ void __launch_bounds__(256) scatter_kernel(const int* __restrict__ ei,
                                                      int* __restrict__ cursor,
                                                      int* __restrict__ list, int E, int N) {
    int e = blockIdx.x * 256 + threadIdx.x;
    if (e < E) {
        int tgt = ei[E + e];
        int p = atomicAdd(&cursor[tgt], 1);
        list[p] = e;                                // '+' contribution
        int src = ei[e];
        int q = atomicAdd(&cursor[src], 1);
        list[q] = e | (int)0x80000000u;             // '-' contribution
    }
}

// ---------------------------------------------------------------------------
// edge MLP via MFMA, OPERAND-SWAPPED: D = W^T @ X^T so each lane owns one
// (edge,batch) row of the output. 16-row tiles: row = e_local*4 + b.
// h output layout: [e][b][30] bf16.
// USE_XB: load pre-converted bf16 x (2 dwordx4 loads, zero packing).
// ---------------------------------------------------------------------------
template<bool USE_XB>
__global__ void __launch_bounds__(256) edge_mlp_mfma2(
    const float* __restrict__ x, const ushort* __restrict__ xb,
    const int* __restrict__ ei, const float* __restrict__ ea,
    const float* __restrict__ W1, const float* __restrict__ b1,
    const float* __restrict__ W2, const float* __restrict__ b2,
    const float* __restrict__ sums, ushort* __restrict__ h,
    int E, int N, int tiles) {
    // per-wave LDS bounce for h1 (row stride 40 ushorts = 80 B)
    __shared__ ushort __attribute__((aligned(16))) hbuf[4][16 * 40];
    int w = threadIdx.x >> 6;
    int lane = threadIdx.x & 63;
    int n16 = lane & 15;
    int q = lane >> 4;

    // weight fragments used as operand A (= W^T):
    // A[m=16t+n16][k=32s+q*8+j] = W1[k][m]  (same data as B-fragment form)
    Frag w1f[2][2];
#pragma unroll
    for (int t = 0; t < 2; t++)
#pragma unroll
        for (int s = 0; s < 2; s++)
#pragma unroll
            for (int j = 0; j < 4; j++) {
                int k0 = 32 * s + q * 8 + 2 * j;
                w1f[t][s].u[j] = pk2(W1[(size_t)k0 * 32 + 16 * t + n16],
                                     W1[(size_t)(k0 + 1) * 32 + 16 * t + n16]);
            }
    Frag w2f[2];
#pragma unroll
    for (int t = 0; t < 2; t++) {
        int m = 16 * t + n16;
#pragma unroll
        for (int j = 0; j < 4; j++) {
            int k0 = q * 8 + 2 * j;
            float a = (m < H2_F) ? W2[(size_t)k0 * H2_F + m] : 0.f;
            float d = (m < H2_F) ? W2[(size_t)(k0 + 1) * H2_F + m] : 0.f;
            w2f[t].u[j] = pk2(a, d);
        }
    }
    // per-lane init constants: C rows of this lane are cols 16t+q*4+r
    float b1q[2][4], w1Lq[2][4], b2q[2][4];
#pragma unroll
    for (int t = 0; t < 2; t++)
#pragma unroll
        for (int r = 0; r < 4; r++) {
            int col = 16 * t + q * 4 + r;
            b1q[t][r]  = b1[col];
            w1Lq[t][r] = W1[(size_t)64 * 32 + col];
            b2q[t][r]  = (col < H2_F) ? b2[col] : 0.f;
        }

    float mean = sums[0] / (float)E;
    float var = (sums[1] - (float)E * mean * mean) / (float)(E - 1);
    float istd = rsqrtf(var);

    int b = n16 & 3;        // batch of this lane's row
    int eoff = n16 >> 2;    // edge offset within tile
    int gw = blockIdx.x * 4 + w;

    for (int tix = 0; tix < TPW; ++tix) {
        int tile = gw * TPW + tix;
        if (tile >= tiles) break;
        int e0 = tile * 4;
        int eA = e0 + eoff;
        bool vrow = eA < E;
        int eAc = vrow ? eA : E - 1;
        int src = ei[eAc], tgt = ei[E + eAc];
        float eav = (ea[eAc] - mean) * istd;

        // B-operand: this lane's row feats q*8..q*8+7 of src / tgt
        Frag a0, a1;
        if (USE_XB) {
            *(uint4*)&a0.u[0] = *(const uint4*)(xb + ((size_t)b * N + src) * IN_F + q * 8);
            *(uint4*)&a1.u[0] = *(const uint4*)(xb + ((size_t)b * N + tgt) * IN_F + q * 8);
        } else {
            const float4* ps = (const float4*)(x + ((size_t)b * N + src) * IN_F + q * 8);
            float4 s0 = ps[0], s1 = ps[1];
            const float4* pt = (const float4*)(x + ((size_t)b * N + tgt) * IN_F + q * 8);
            float4 t0 = pt[0], t1 = pt[1];
            a0.u[0] = pk2(s0.x, s0.y); a0.u[1] = pk2(s0.z, s0.w);
            a0.u[2] = pk2(s1.x, s1.y); a0.u[3] = pk2(s1.z, s1.w);
            a1.u[0] = pk2(t0.x, t0.y); a1.u[1] = pk2(t0.z, t0.w);
            a1.u[2] = pk2(t1.x, t1.y); a1.u[3] = pk2(t1.z, t1.w);
        }

        // layer 1: D[m=h1col][n=edge-row]; init = b1 + eav*W1[64]
        f32x4 acc0, acc1;
#pragma unroll
        for (int r = 0; r < 4; r++) {
            acc0[r] = b1q[0][r] + eav * w1Lq[0][r];
            acc1[r] = b1q[1][r] + eav * w1Lq[1][r];
        }
        acc0 = __builtin_amdgcn_mfma_f32_16x16x32_bf16(w1f[0][0].v, a0.v, acc0, 0, 0, 0);
        acc0 = __builtin_amdgcn_mfma_f32_16x16x32_bf16(w1f[0][1].v, a1.v, acc0, 0, 0, 0);
        acc1 = __builtin_amdgcn_mfma_f32_16x16x32_bf16(w1f[1][0].v, a0.v, acc1, 0, 0, 0);
        acc1 = __builtin_amdgcn_mfma_f32_16x16x32_bf16(w1f[1][1].v, a1.v, acc1, 0, 0, 0);

        // lane holds h1[row n16][cols 16t+q*4+r] -> sigmoid, pack, b64 to LDS
        uint u0 = pk2(sigmoidf_(acc0[0]), sigmoidf_(acc0[1]));
        uint u1 = pk2(sigmoidf_(acc0[2]), sigmoidf_(acc0[3]));
        uint u2 = pk2(sigmoidf_(acc1[0]), sigmoidf_(acc1[1]));
        uint u3 = pk2(sigmoidf_(acc1[2]), sigmoidf_(acc1[3]));
        uint2 p01 = {u0, u1}, p23 = {u2, u3};
        *(uint2*)&hbuf[w][n16 * 40 + q * 4]      = p01;   // cols q*4..q*4+3
        *(uint2*)&hbuf[w][n16 * 40 + 16 + q * 4] = p23;   // cols 16+q*4..

        // layer-2 B-operand: h1[row n16][k=q*8..q*8+7], one b128
        Frag ha;
        *(uint4*)&ha.u[0] = *(const uint4*)&hbuf[w][n16 * 40 + q * 8];

        f32x4 c0, c1;
#pragma unroll
        for (int r = 0; r < 4; r++) { c0[r] = b2q[0][r]; c1[r] = b2q[1][r]; }
        c0 = __builtin_amdgcn_mfma_f32_16x16x32_bf16(w2f[0].v, ha.v, c0, 0, 0, 0);
        c1 = __builtin_amdgcn_mfma_f32_16x16x32_bf16(w2f[1].v, ha.v, c1, 0, 0, 0);

        // lane holds h2[row n16][cols q*4+r, 16+q*4+r] -> direct global store
        uint g0 = pk2(sigmoidf_(c0[0]), sigmoidf_(c0[1]));
        uint g1 = pk2(sigmoidf_(c0[2]), sigmoidf_(c0[3]));
        uint g2 = pk2(sigmoidf_(c1[0]), sigmoidf_(c1[1]));
        uint g3 = pk2(sigmoidf_(c1[2]), sigmoidf_(c1[3]));  // q==3: cols 30,31 invalid
        if (vrow) {
            uint* base = (uint*)(h + (size_t)(e0 * 4 + n16) * H2_F);
            base[q * 2]     = g0;
            base[q * 2 + 1] = g1;
            base[8 + q * 2] = g2;
            if (q < 3) base[8 + q * 2 + 1] = g3;
        }
    }
}

// ---------------------------------------------------------------------------
// gather + fused W3: one wave per node; signed combined list
// ---------------------------------------------------------------------------
__global__ void __launch_bounds__(256) gather_final(
    const ushort* __restrict__ h, const int* __restrict__ list,
    const int* __restrict__ offs, const float* __restrict__ W3,
    const float* __restrict__ b3, float* __restrict__ out, int N) {
    __shared__ float sW3[H2_F * 32];
    __shared__ float sb3[32];
    __shared__ float sacc[4][B_SZ][H2_F];
    for (int i = threadIdx.x; i < H2_F * 32; i += 256) sW3[i] = W3[i];
    if (threadIdx.x < 32) sb3[threadIdx.x] = b3[threadIdx.x];
    __syncthreads();

    int w = threadIdx.x >> 6, lane = threadIdx.x & 63;
    int n = blockIdx.x * 4 + w;
    if (n >= N) return;

    if (lane < 60) {
        int bq = lane / 15, jp = lane % 15;
        float a0 = 0.f, a1 = 0.f;
        int s = offs[n], e = offs[n + 1];
        int i = s;
        for (; i + 4 <= e; i += 4) {
            int v0 = list[i], v1 = list[i + 1], v2 = list[i + 2], v3 = list[i + 3];
            uint d0 = *(const uint*)(h + (size_t)(v0 & 0x7FFFFFFF) * 120 + bq * 30 + jp * 2);
            uint d1 = *(const uint*)(h + (size_t)(v1 & 0x7FFFFFFF) * 120 + bq * 30 + jp * 2);
            uint d2 = *(const uint*)(h + (size_t)(v2 & 0x7FFFFFFF) * 120 + bq * 30 + jp * 2);
            uint d3 = *(const uint*)(h + (size_t)(v3 & 0x7FFFFFFF) * 120 + bq * 30 + jp * 2);
            float g0 = (v0 < 0) ? -1.f : 1.f;
            float g1 = (v1 < 0) ? -1.f : 1.f;
            float g2 = (v2 < 0) ? -1.f : 1.f;
            float g3 = (v3 < 0) ? -1.f : 1.f;
            a0 += g0 * bf2f((ushort)d0) + g1 * bf2f((ushort)d1)
                + g2 * bf2f((ushort)d2) + g3 * bf2f((ushort)d3);
            a1 += g0 * bf2f((ushort)(d0 >> 16)) + g1 * bf2f((ushort)(d1 >> 16))
                + g2 * bf2f((ushort)(d2 >> 16)) + g3 * bf2f((ushort)(d3 >> 16));
        }
        for (; i < e; i++) {
            int v = list[i];
            uint d = *(const uint*)(h + (size_t)(v & 0x7FFFFFFF) * 120 + bq * 30 + jp * 2);
            float g = (v < 0) ? -1.f : 1.f;
            a0 += g * bf2f((ushort)d);
            a1 += g * bf2f((ushort)(d >> 16));
        }
        sacc[w][bq][jp * 2]     = a0;
        sacc[w][bq][jp * 2 + 1] = a1;
    }
    // wave-synchronous epilogue
    int b = lane >> 4, k = lane & 15;
    float o0 = sb3[k], o1 = sb3[k + 16];
#pragma unroll
    for (int j = 0; j < H2_F; j++) {
        float v = sacc[w][b][j];
        o0 += v * sW3[j * 32 + k];
        o1 += v * sW3[j * 32 + k + 16];
    }
    float* op = out + ((size_t)b * N + n) * 32;
    op[k]      = sigmoidf_(o0);
    op[k + 16] = sigmoidf_(o1);
}

// ---------------------------------------------------------------------------
// fallback (small ws): round-1 atomic path
// ---------------------------------------------------------------------------
__global__ void __launch_bounds__(256) edge_kernel_atomic(
    const float* __restrict__ x, const int* __restrict__ ei,
    const float* __restrict__ ea,
    const float* __restrict__ W1, const float* __restrict__ b1,
    const float* __restrict__ W2, const float* __restrict__ b2,
    const float* __restrict__ sums, float* __restrict__ acc, int E, int N) {
    __shared__ float sW1[(2 * IN_F + 1) * H1_F];
    __shared__ float sb1[H1_F];
    __shared__ float sW2[H1_F * H2_F];
    __shared__ float sb2[H2_F];
    for (int i = threadIdx.x; i < (2 * IN_F + 1) * H1_F; i += 256) sW1[i] = W1[i];
    for (int i = threadIdx.x; i < H1_F * H2_F; i += 256) sW2[i] = W2[i];
    if (threadIdx.x < H1_F) sb1[threadIdx.x] = b1[threadIdx.x];
    if (threadIdx.x < H2_F) sb2[threadIdx.x] = b2[threadIdx.x];
    __syncthreads();
    long long gid = (long long)blockIdx.x * 256 + threadIdx.x;
    if (gid >= (long long)B_SZ * E) return;
    int e = (int)(gid >> 2);
    int b = (int)(gid & 3);
    int src = ei[e];
    int tgt = ei[E + e];
    float s1 = sums[0], s2 = sums[1];
    float mean = s1 / (float)E;
    float var = (s2 - (float)E * mean * mean) / (float)(E - 1);
    float eav = (ea[e] - mean) * rsqrtf(var);
    float h1[H1_F];
#pragma unroll
    for (int j = 0; j < H1_F; j++) h1[j] = sb1[j] + eav * sW1[2 * IN_F * H1_F + j];
    const float4* xs4 = (const float4*)(x + ((size_t)b * N + src) * IN_F);
    const float4* xt4 = (const float4*)(x + ((size_t)b * N + tgt) * IN_F);
#pragma unroll
    for (int i4 = 0; i4 < IN_F / 4; i4++) {
        float4 a = xs4[i4];
        float4 c = xt4[i4];
        const float* w_s = &sW1[(i4 * 4) * H1_F];
        const float* w_t = &sW1[(IN_F + i4 * 4) * H1_F];
#pragma unroll
        for (int j = 0; j < H1_F; j++) {
            h1[j] += a.x * w_s[j] + a.y * w_s[H1_F + j] + a.z * w_s[2 * H1_F + j]
                   + a.w * w_s[3 * H1_F + j] + c.x * w_t[j] + c.y * w_t[H1_F + j]
                   + c.z * w_t[2 * H1_F + j] + c.w * w_t[3 * H1_F + j];
        }
    }
#pragma unroll
    for (int i = 0; i < H1_F; i++) h1[i] = sigmoidf_(h1[i]);
    float h2[H2_F];
#pragma unroll
    for (int j = 0; j < H2_F; j++) h2[j] = sb2[j];
#pragma unroll
    for (int i = 0; i < H1_F; i++) {
        float a = h1[i];
#pragma unroll
        for (int j = 0; j < H2_F; j++) h2[j] += a * sW2[i * H2_F + j];
    }
    float* at = acc + ((size_t)b * N + tgt) * H2_F;
    float* as = acc + ((size_t)b * N + src) * H2_F;
#pragma unroll
    for (int j = 0; j < H2_F; j++) {
        float hv = sigmoidf_(h2[j]);
        unsafeAtomicAdd(at + j, hv);
        unsafeAtomicAdd(as + j, -hv);
    }
}

__global__ void __launch_bounds__(256) final_kernel(const float* __restrict__ acc,
                                                    const float* __restrict__ W3,
                                                    const float* __restrict__ b3,
                                                    float* __restrict__ out, int BN) {
    __shared__ float sW3[H2_F * 32];
    __shared__ float sb3[32];
    __shared__ float srow[8][H2_F];
    for (int i = threadIdx.x; i < H2_F * 32; i += 256) sW3[i] = W3[i];
    if (threadIdx.x < 32) sb3[threadIdx.x] = b3[threadIdx.x];
    int row0 = blockIdx.x * 8;
    for (int i = threadIdx.x; i < 8 * H2_F; i += 256) {
        int r = i / H2_F, k = i % H2_F;
        int rr = row0 + r;
        srow[r][k] = (rr < BN) ? acc[(size_t)rr * H2_F + k] : 0.f;
    }
    __syncthreads();
    int r = threadIdx.x >> 5;
    int j = threadIdx.x & 31;
    int row = row0 + r;
    if (row < BN) {
        float a = sb3[j];
#pragma unroll
        for (int k = 0; k < H2_F; k++) a += srow[r][k] * sW3[k * 32 + j];
        out[(size_t)row * 32 + j] = sigmoidf_(a);
    }
}

// ---------------------------------------------------------------------------
extern "C" void kernel_launch(void* const* d_in, const int* in_sizes, int n_in,
                              void* d_out, int out_size, void* d_ws, size_t ws_size,
                              hipStream_t stream) {
    const float* x  = (const float*)d_in[0];
    const int*   ei = (const int*)d_in[1];
    const float* ea = (const float*)d_in[2];
    const float* W1 = (const float*)d_in[3];
    const float* b1 = (const float*)d_in[4];
    const float* W2 = (const float*)d_in[5];
    const float* b2 = (const float*)d_in[6];
    const float* W3 = (const float*)d_in[7];
    const float* b3 = (const float*)d_in[8];
    float* out = (float*)d_out;

    const int E  = in_sizes[2];
    const int N  = in_sizes[0] / (B_SZ * IN_F);
    const int BN = B_SZ * N;

    // ws layout: h [E*4*30 bf16] | list [2E] | cnt [N] | offs [N+1] | cursor [N]
    //            | bsum [1024] | sums [2] | xb [B*N*32 bf16]
    ushort* h   = (ushort*)d_ws;
    int* list   = (int*)((char*)d_ws + (size_t)E * 120 * sizeof(ushort));
    int* cnt    = list + 2 * (size_t)E;
    int* offs   = cnt + N;
    int* cursor = offs + N + 1;
    int* bsum   = cursor + N;
    float* sums = (float*)(bsum + 1024);
    ushort* xb  = (ushort*)(sums + 2);
    size_t need1 = (size_t)((char*)(sums + 2) - (char*)d_ws);
    size_t need2 = need1 + (size_t)BN * IN_F * sizeof(ushort);

    if (ws_size >= need1) {
        bool use_xb = (ws_size >= need2);
        hipMemsetAsync(cnt, 0, (size_t)N * sizeof(int), stream);
        hipMemsetAsync(sums, 0, 2 * sizeof(float), stream);

        stats_kernel<<<256, 256, 0, stream>>>(ea, sums, E);
        if (use_xb) {
            long long n8 = (long long)BN * IN_F / 8;
            xcvt_kernel<<<(int)((n8 + 255) / 256), 256, 0, stream>>>(x, xb, n8);
        }
        hist_kernel<<<(E + 255) / 256, 256, 0, stream>>>(ei, cnt, E, N);
        int nb = (N + 1023) / 1024;
        scan1_kernel<<<nb, 256, 0, stream>>>(cnt, offs, bsum, N);
        scan2_kernel<<<1, 64, 0, stream>>>(bsum, offs, nb, N);
        scan3_kernel<<<nb, 256, 0, stream>>>(offs, cursor, bsum, N);
        scatter_kernel<<<(E + 255) / 256, 256, 0, stream>>>(ei, cursor, list, E, N);

        int tiles = (E + 3) / 4;
        int waves = (tiles + TPW - 1) / TPW;
        int blocks = (waves + 3) / 4;
        if (use_xb)
            edge_mlp_mfma2<true><<<blocks, 256, 0, stream>>>(x, xb, ei, ea, W1, b1,
                                                             W2, b2, sums, h, E, N, tiles);
        else
            edge_mlp_mfma2<false><<<blocks, 256, 0, stream>>>(x, xb, ei, ea, W1, b1,
                                                              W2, b2, sums, h, E, N, tiles);
        gather_final<<<(N + 3) / 4, 256, 0, stream>>>(h, list, offs, W3, b3, out, N);
    } else {
        float* acc   = (float*)d_ws;
        float* sumsF = acc + (size_t)BN * H2_F;
        hipMemsetAsync(d_ws, 0,
                       (size_t)BN * H2_F * sizeof(float) + 2 * sizeof(float), stream);
        stats_kernel<<<256, 256, 0, stream>>>(ea, sumsF, E);
        long long total = (long long)B_SZ * E;
        int blocks = (int)((total + 255) / 256);
        edge_kernel_atomic<<<blocks, 256, 0, stream>>>(x, ei, ea, W1, b1, W2, b2,
                                                       sumsF, acc, E, N);
        final_kernel<<<(BN + 7) / 8, 256, 0, stream>>>(acc, W3, b3, out, BN);
    }
}

// Round 5
// 570.063 us; speedup vs baseline: 17.0237x; 1.0224x over previous
//
#include <hip/hip_runtime.h>
#include <math.h>

#define B_SZ 4
#define IN_F 32
#define H1_F 32
#define H2_F 30
#define TPW 16   // row-tiles per wave in edge kernel

typedef unsigned int uint;
typedef unsigned short ushort;
typedef __attribute__((ext_vector_type(8))) short bf16x8;
typedef __attribute__((ext_vector_type(4))) float f32x4;

__device__ __forceinline__ float fastrcp(float x) {
#if __has_builtin(__builtin_amdgcn_rcpf)
    return __builtin_amdgcn_rcpf(x);   // v_rcp_f32, avoids IEEE div sequence
#else
    return 1.f / x;
#endif
}
__device__ __forceinline__ float sigmoidf_(float x) {
    return fastrcp(1.f + __expf(-x));
}

__device__ __forceinline__ ushort f2bf(float f) {
    uint u = __float_as_uint(f);
    return (ushort)((u + 0x7FFFu + ((u >> 16) & 1u)) >> 16);  // RNE
}
__device__ __forceinline__ float bf2f(ushort v) { return __uint_as_float(((uint)v) << 16); }
__device__ __forceinline__ uint pk2(float a, float b) {
    return (uint)f2bf(a) | ((uint)f2bf(b) << 16);
}

union Frag { bf16x8 v; ushort us[8]; uint u[4]; };

// ---------------------------------------------------------------------------
// fused stats (mean/sumsq of ea) + degree histogram (tgt+src combined)
// ---------------------------------------------------------------------------
__global__ void __launch_bounds__(256) stats_hist_kernel(
    const float* __restrict__ ea, const int* __restrict__ ei,
    float* __restrict__ sums, int* __restrict__ cnt, int E, int N) {
    int e = blockIdx.x * 256 + threadIdx.x;
    float a = (e < E) ? ea[e] : 0.f;
    if (e < E) {
        atomicAdd(&cnt[ei[E + e]], 1);
        atomicAdd(&cnt[ei[e]], 1);
    }
    float v = a, v2 = a * a;
    for (int off = 32; off > 0; off >>= 1) {
        v  += __shfl_down(v, off);
        v2 += __shfl_down(v2, off);
    }
    __shared__ float s1[4], s2[4];
    int wid = threadIdx.x >> 6, lane = threadIdx.x & 63;
    if (lane == 0) { s1[wid] = v; s2[wid] = v2; }
    __syncthreads();
    if (threadIdx.x == 0) {
        unsafeAtomicAdd(&sums[0], s1[0] + s1[1] + s1[2] + s1[3]);
        unsafeAtomicAdd(&sums[1], s2[0] + s2[1] + s2[2] + s2[3]);
    }
}

// ---------------------------------------------------------------------------
// x f32 -> bf16 conversion (8 elems/thread)
// ---------------------------------------------------------------------------
__global__ void __launch_bounds__(256) xcvt_kernel(const float* __restrict__ x,
                                                   ushort* __restrict__ xb,
                                                   long long n8) {
    long long i = (long long)blockIdx.x * 256 + threadIdx.x;
    if (i >= n8) return;
    const float4* p = (const float4*)(x + i * 8);
    float4 v0 = p[0], v1 = p[1];
    uint4 o;
    o.x = pk2(v0.x, v0.y); o.y = pk2(v0.z, v0.w);
    o.z = pk2(v1.x, v1.y); o.w = pk2(v1.z, v1.w);
    *(uint4*)(xb + i * 8) = o;
}

// ---------------------------------------------------------------------------
// 3-phase multi-block exclusive scan (1024 elems/block)
// ---------------------------------------------------------------------------
__global__ void __launch_bounds__(256) scan1_kernel(const int* __restrict__ cnt,
                                                    int* __restrict__ offs,
                                                    int* __restrict__ bsum, int n) {
    __shared__ int wtot[4];
    int base = blockIdx.x * 1024 + threadIdx.x * 4;
    int4 v = {0, 0, 0, 0};
    if (base + 3 < n) v = *(const int4*)(cnt + base);
    else {
        if (base < n)     v.x = cnt[base];
        if (base + 1 < n) v.y = cnt[base + 1];
        if (base + 2 < n) v.z = cnt[base + 2];
        if (base + 3 < n) v.w = cnt[base + 3];
    }
    int s = v.x + v.y + v.z + v.w;
    int incl = s;
    int lane = threadIdx.x & 63;
    for (int d = 1; d < 64; d <<= 1) {
        int t = __shfl_up(incl, d);
        if (lane >= d) incl += t;
    }
    int wid = threadIdx.x >> 6;
    if (lane == 63) wtot[wid] = incl;
    __syncthreads();
    int woff = 0, tot = 0;
#pragma unroll
    for (int w = 0; w < 4; w++) {
        int t = wtot[w];
        if (w < wid) woff += t;
        tot += t;
    }
    int excl = woff + incl - s;
    int4 o;
    o.x = excl; o.y = excl + v.x; o.z = o.y + v.y; o.w = o.z + v.z;
    if (base + 3 < n) *(int4*)(offs + base) = o;
    else {
        if (base < n)     offs[base] = o.x;
        if (base + 1 < n) offs[base + 1] = o.y;
        if (base + 2 < n) offs[base + 2] = o.z;
        if (base + 3 < n) offs[base + 3] = o.w;
    }
    if (threadIdx.x == 0) bsum[blockIdx.x] = tot;
}

__global__ void scan2_kernel(int* __restrict__ bsum, int* __restrict__ offs,
                             int nb, int n) {
    int lane = threadIdx.x;
    if (nb <= 64) {
        int v = (lane < nb) ? bsum[lane] : 0;
        int incl = v;
        for (int d = 1; d < 64; d <<= 1) {
            int t = __shfl_up(incl, d);
            if (lane >= d) incl += t;
        }
        if (lane < nb) bsum[lane] = incl - v;
        if (lane == 63) offs[n] = incl;
    } else if (lane == 0) {
        int run = 0;
        for (int i = 0; i < nb; i++) { int t = bsum[i]; bsum[i] = run; run += t; }
        offs[n] = run;
    }
}

__global__ void __launch_bounds__(256) scan3_kernel(int* __restrict__ offs,
                                                    int* __restrict__ cursor,
                                                    const int* __restrict__ bsum, int n) {
    int base = blockIdx.x * 1024 + threadIdx.x * 4;
    int add = bsum[blockIdx.x];
    if (base + 3 < n) {
        int4 v = *(const int4*)(offs + base);
        v.x += add; v.y += add; v.z += add; v.w += add;
        *(int4*)(offs + base) = v;
        *(int4*)(cursor + base) = v;
    } else {
        for (int k = 0; k < 4; k++) {
            int i = base + k;
            if (i < n) { int v = offs[i] + add; offs[i] = v; cursor[i] = v; }
        }
    }
}

// ---------------------------------------------------------------------------
// NEW: edge MLP (operand-swapped MFMA) writing h DIRECTLY into CSR slots.
// Per edge: +h -> slot(tgt), -h -> slot(src) via pipelined cursor atomics.
// Slot layout: [slot][b][30] bf16, 240 B/slot. Gather becomes sequential.
// ---------------------------------------------------------------------------
__global__ void __launch_bounds__(256) edge_mlp_mfma3(
    const ushort* __restrict__ xb,
    const int* __restrict__ ei, const float* __restrict__ ea,
    const float* __restrict__ W1, const float* __restrict__ b1,
    const float* __restrict__ W2, const float* __restrict__ b2,
    const float* __restrict__ sums, int* __restrict__ cursor,
    ushort* __restrict__ h, int E, int N, int tiles) {
    __shared__ ushort __attribute__((aligned(16))) hbuf[4][16 * 40];
    int w = threadIdx.x >> 6;
    int lane = threadIdx.x & 63;
    int n16 = lane & 15;
    int q = lane >> 4;

    // weight fragments as operand A (= W^T)
    Frag w1f[2][2];
#pragma unroll
    for (int t = 0; t < 2; t++)
#pragma unroll
        for (int s = 0; s < 2; s++)
#pragma unroll
            for (int j = 0; j < 4; j++) {
                int k0 = 32 * s + q * 8 + 2 * j;
                w1f[t][s].u[j] = pk2(W1[(size_t)k0 * 32 + 16 * t + n16],
                                     W1[(size_t)(k0 + 1) * 32 + 16 * t + n16]);
            }
    Frag w2f[2];
#pragma unroll
    for (int t = 0; t < 2; t++) {
        int m = 16 * t + n16;
#pragma unroll
        for (int j = 0; j < 4; j++) {
            int k0 = q * 8 + 2 * j;
            float a = (m < H2_F) ? W2[(size_t)k0 * H2_F + m] : 0.f;
            float d = (m < H2_F) ? W2[(size_t)(k0 + 1) * H2_F + m] : 0.f;
            w2f[t].u[j] = pk2(a, d);
        }
    }
    float b1q[2][4], w1Lq[2][4], b2q[2][4];
#pragma unroll
    for (int t = 0; t < 2; t++)
#pragma unroll
        for (int r = 0; r < 4; r++) {
            int col = 16 * t + q * 4 + r;
            b1q[t][r]  = b1[col];
            w1Lq[t][r] = W1[(size_t)64 * 32 + col];
            b2q[t][r]  = (col < H2_F) ? b2[col] : 0.f;
        }

    float mean = sums[0] / (float)E;
    float var = (sums[1] - (float)E * mean * mean) / (float)(E - 1);
    float istd = rsqrtf(var);

    int b = n16 & 3;
    int eoff = n16 >> 2;
    int gw = blockIdx.x * 4 + w;
    int tile0 = gw * TPW;
    if (tile0 >= tiles) return;

    // ---- software pipeline: meta + xb + slot-atomic one tile ahead ----
    int src, tgt; float eav; bool vrow; Frag a0, a1; int slotraw;
    {
        int eA = tile0 * 4 + eoff; vrow = eA < E; int c = vrow ? eA : E - 1;
        src = ei[c]; tgt = ei[E + c]; eav = (ea[c] - mean) * istd;
        *(uint4*)&a0.u[0] = *(const uint4*)(xb + ((size_t)b * N + src) * IN_F + q * 8);
        *(uint4*)&a1.u[0] = *(const uint4*)(xb + ((size_t)b * N + tgt) * IN_F + q * 8);
        int el = (lane >> 1) & 3;
        int nt = __shfl(tgt, el * 4);
        int ns = __shfl(src, el * 4);
        slotraw = 0;
        if (lane < 8 && tile0 * 4 + el < E)
            slotraw = atomicAdd(&cursor[(lane & 1) ? ns : nt], 1);
    }

    for (int tix = 0; tix < TPW; ++tix) {
        int tile = tile0 + tix;
        if (tile >= tiles) break;

        // prefetch next tile
        int nsrc = 0, ntgt = 0; float neav = 0.f; bool nvrow = false; int nslot = 0;
        Frag na0, na1;
        na0.u[0] = na0.u[1] = na0.u[2] = na0.u[3] = 0; na1 = na0;
        bool hn = (tix + 1 < TPW) && (tile + 1 < tiles);
        if (hn) {
            int eA = (tile + 1) * 4 + eoff; nvrow = eA < E; int c = nvrow ? eA : E - 1;
            nsrc = ei[c]; ntgt = ei[E + c]; neav = (ea[c] - mean) * istd;
            *(uint4*)&na0.u[0] = *(const uint4*)(xb + ((size_t)b * N + nsrc) * IN_F + q * 8);
            *(uint4*)&na1.u[0] = *(const uint4*)(xb + ((size_t)b * N + ntgt) * IN_F + q * 8);
        }
        {
            int el = (lane >> 1) & 3;
            int nt = __shfl(ntgt, el * 4);
            int ns = __shfl(nsrc, el * 4);
            if (hn && lane < 8 && (tile + 1) * 4 + el < E)
                nslot = atomicAdd(&cursor[(lane & 1) ? ns : nt], 1);
        }

        // ---- compute current tile ----
        f32x4 acc0, acc1;
#pragma unroll
        for (int r = 0; r < 4; r++) {
            acc0[r] = b1q[0][r] + eav * w1Lq[0][r];
            acc1[r] = b1q[1][r] + eav * w1Lq[1][r];
        }
        acc0 = __builtin_amdgcn_mfma_f32_16x16x32_bf16(w1f[0][0].v, a0.v, acc0, 0, 0, 0);
        acc0 = __builtin_amdgcn_mfma_f32_16x16x32_bf16(w1f[0][1].v, a1.v, acc0, 0, 0, 0);
        acc1 = __builtin_amdgcn_mfma_f32_16x16x32_bf16(w1f[1][0].v, a0.v, acc1, 0, 0, 0);
        acc1 = __builtin_amdgcn_mfma_f32_16x16x32_bf16(w1f[1][1].v, a1.v, acc1, 0, 0, 0);

        uint u0 = pk2(sigmoidf_(acc0[0]), sigmoidf_(acc0[1]));
        uint u1 = pk2(sigmoidf_(acc0[2]), sigmoidf_(acc0[3]));
        uint u2 = pk2(sigmoidf_(acc1[0]), sigmoidf_(acc1[1]));
        uint u3 = pk2(sigmoidf_(acc1[2]), sigmoidf_(acc1[3]));
        uint2 p01 = {u0, u1}, p23 = {u2, u3};
        *(uint2*)&hbuf[w][n16 * 40 + q * 4]      = p01;
        *(uint2*)&hbuf[w][n16 * 40 + 16 + q * 4] = p23;

        Frag ha;
        *(uint4*)&ha.u[0] = *(const uint4*)&hbuf[w][n16 * 40 + q * 8];

        f32x4 c0, c1;
#pragma unroll
        for (int r = 0; r < 4; r++) { c0[r] = b2q[0][r]; c1[r] = b2q[1][r]; }
        c0 = __builtin_amdgcn_mfma_f32_16x16x32_bf16(w2f[0].v, ha.v, c0, 0, 0, 0);
        c1 = __builtin_amdgcn_mfma_f32_16x16x32_bf16(w2f[1].v, ha.v, c1, 0, 0, 0);

        uint g0 = pk2(sigmoidf_(c0[0]), sigmoidf_(c0[1]));
        uint g1 = pk2(sigmoidf_(c0[2]), sigmoidf_(c0[3]));
        uint g2 = pk2(sigmoidf_(c1[0]), sigmoidf_(c1[1]));
        uint g3 = pk2(sigmoidf_(c1[2]), sigmoidf_(c1[3]));

        int slot_t = __shfl(slotraw, eoff * 2);
        int slot_s = __shfl(slotraw, eoff * 2 + 1);
        if (vrow) {
            uint* bt = (uint*)(h + (size_t)slot_t * 120 + b * 30);
            bt[q * 2]     = g0;
            bt[q * 2 + 1] = g1;
            bt[8 + q * 2] = g2;
            if (q < 3) bt[8 + q * 2 + 1] = g3;
            uint* bs = (uint*)(h + (size_t)slot_s * 120 + b * 30);
            const uint SM = 0x80008000u;
            bs[q * 2]     = g0 ^ SM;
            bs[q * 2 + 1] = g1 ^ SM;
            bs[8 + q * 2] = g2 ^ SM;
            if (q < 3) bs[8 + q * 2 + 1] = g3 ^ SM;
        }

        src = nsrc; tgt = ntgt; eav = neav; vrow = nvrow;
        a0 = na0; a1 = na1; slotraw = nslot;
    }
}

// ---------------------------------------------------------------------------
// NEW: gather over CONTIGUOUS slots (signs baked in) + fused W3 epilogue
// ---------------------------------------------------------------------------
__global__ void __launch_bounds__(256) gather_final2(
    const ushort* __restrict__ h, const int* __restrict__ offs,
    const float* __restrict__ W3, const float* __restrict__ b3,
    float* __restrict__ out, int N) {
    __shared__ float sW3[H2_F * 32];
    __shared__ float sb3[32];
    __shared__ float sacc[4][B_SZ][H2_F];
    for (int i = threadIdx.x; i < H2_F * 32; i += 256) sW3[i] = W3[i];
    if (threadIdx.x < 32) sb3[threadIdx.x] = b3[threadIdx.x];
    __syncthreads();

    int w = threadIdx.x >> 6, lane = threadIdx.x & 63;
    int n = blockIdx.x * 4 + w;
    if (n >= N) return;

    int s = offs[n], e = offs[n + 1];
    if (lane < 60) {
        int bq = lane / 15, jp = lane % 15;
        const ushort* p = h + (size_t)s * 120 + bq * 30 + jp * 2;
        float a0 = 0.f, a1 = 0.f;
        int cnt = e - s;
        int i = 0;
        for (; i + 4 <= cnt; i += 4) {
            uint d0 = *(const uint*)(p);
            uint d1 = *(const uint*)(p + 120);
            uint d2 = *(const uint*)(p + 240);
            uint d3 = *(const uint*)(p + 360);
            p += 480;
            a0 += bf2f((ushort)d0) + bf2f((ushort)d1)
                + bf2f((ushort)d2) + bf2f((ushort)d3);
            a1 += bf2f((ushort)(d0 >> 16)) + bf2f((ushort)(d1 >> 16))
                + bf2f((ushort)(d2 >> 16)) + bf2f((ushort)(d3 >> 16));
        }
        for (; i < cnt; i++) {
            uint d = *(const uint*)(p);
            p += 120;
            a0 += bf2f((ushort)d);
            a1 += bf2f((ushort)(d >> 16));
        }
        sacc[w][bq][jp * 2]     = a0;
        sacc[w][bq][jp * 2 + 1] = a1;
    }
    // wave-synchronous epilogue
    int b = lane >> 4, k = lane & 15;
    float o0 = sb3[k], o1 = sb3[k + 16];
#pragma unroll
    for (int j = 0; j < H2_F; j++) {
        float v = sacc[w][b][j];
        o0 += v * sW3[j * 32 + k];
        o1 += v * sW3[j * 32 + k + 16];
    }
    float* op = out + ((size_t)b * N + n) * 32;
    op[k]      = sigmoidf_(o0);
    op[k + 16] = sigmoidf_(o1);
}

// ---------------------------------------------------------------------------
// FALLBACK tier (round-4 path): scatter list + list-indirect gather
// ---------------------------------------------------------------------------
__global__ void __launch_bounds__(256) scatter_kernel(const int* __restrict__ ei,
                                                      int* __restrict__ cursor,
                                                      int* __restrict__ list, int E, int N) {
    int e = blockIdx.x * 256 + threadIdx.x;
    if (e < E) {
        int tgt = ei[E + e];
        int p = atomicAdd(&cursor[tgt], 1);
        list[p] = e;
        int src = ei[e];
        int q = atomicAdd(&cursor[src], 1);
        list[q] = e | (int)0x80000000u;
    }
}

template<bool USE_XB>
__global__ void __launch_bounds__(256) edge_mlp_mfma2(
    const float* __restrict__ x, const ushort* __restrict__ xb,
    const int* __restrict__ ei, const float* __restrict__ ea,
    const float* __restrict__ W1, const float* __restrict__ b1,
    const float* __restrict__ W2, const float* __restrict__ b2,
    const float* __restrict__ sums, ushort* __restrict__ h,
    int E, int N, int tiles) {
    __shared__ ushort __attribute__((aligned(16))) hbuf[4][16 * 40];
    int w = threadIdx.x >> 6;
    int lane = threadIdx.x & 63;
    int n16 = lane & 15;
    int q = lane >> 4;

    Frag w1f[2][2];
#pragma unroll
    for (int t = 0; t < 2; t++)
#pragma unroll
        for (int s = 0; s < 2; s++)
#pragma unroll
            for (int j = 0; j < 4; j++) {
                int k0 = 32 * s + q * 8 + 2 * j;
                w1f[t][s].u[j] = pk2(W1[(size_t)k0 * 32 + 16 * t + n16],
                                     W1[(size_t)(k0 + 1) * 32 + 16 * t + n16]);
            }
    Frag w2f[2];
#pragma unroll
    for (int t = 0; t < 2; t++) {
        int m = 16 * t + n16;
#pragma unroll
        for (int j = 0; j < 4; j++) {
            int k0 = q * 8 + 2 * j;
            float a = (m < H2_F) ? W2[(size_t)k0 * H2_F + m] : 0.f;
            float d = (m < H2_F) ? W2[(size_t)(k0 + 1) * H2_F + m] : 0.f;
            w2f[t].u[j] = pk2(a, d);
        }
    }
    float b1q[2][4], w1Lq[2][4], b2q[2][4];
#pragma unroll
    for (int t = 0; t < 2; t++)
#pragma unroll
        for (int r = 0; r < 4; r++) {
            int col = 16 * t + q * 4 + r;
            b1q[t][r]  = b1[col];
            w1Lq[t][r] = W1[(size_t)64 * 32 + col];
            b2q[t][r]  = (col < H2_F) ? b2[col] : 0.f;
        }

    float mean = sums[0] / (float)E;
    float var = (sums[1] - (float)E * mean * mean) / (float)(E - 1);
    float istd = rsqrtf(var);

    int b = n16 & 3;
    int eoff = n16 >> 2;
    int gw = blockIdx.x * 4 + w;

    for (int tix = 0; tix < TPW; ++tix) {
        int tile = gw * TPW + tix;
        if (tile >= tiles) break;
        int e0 = tile * 4;
        int eA = e0 + eoff;
        bool vrow = eA < E;
        int eAc = vrow ? eA : E - 1;
        int src = ei[eAc], tgt = ei[E + eAc];
        float eav = (ea[eAc] - mean) * istd;

        Frag a0, a1;
        if (USE_XB) {
            *(uint4*)&a0.u[0] = *(const uint4*)(xb + ((size_t)b * N + src) * IN_F + q * 8);
            *(uint4*)&a1.u[0] = *(const uint4*)(xb + ((size_t)b * N + tgt) * IN_F + q * 8);
        } else {
            const float4* ps = (const float4*)(x + ((size_t)b * N + src) * IN_F + q * 8);
            float4 s0 = ps[0], s1 = ps[1];
            const float4* pt = (const float4*)(x + ((size_t)b * N + tgt) * IN_F + q * 8);
            float4 t0 = pt[0], t1 = pt[1];
            a0.u[0] = pk2(s0.x, s0.y); a0.u[1] = pk2(s0.z, s0.w);
            a0.u[2] = pk2(s1.x, s1.y); a0.u[3] = pk2(s1.z, s1.w);
            a1.u[0] = pk2(t0.x, t0.y); a1.u[1] = pk2(t0.z, t0.w);
            a1.u[2] = pk2(t1.x, t1.y); a1.u[3] = pk2(t1.z, t1.w);
        }

        f32x4 acc0, acc1;
#pragma unroll
        for (int r = 0; r < 4; r++) {
            acc0[r] = b1q[0][r] + eav * w1Lq[0][r];
            acc1[r] = b1q[1][r] + eav * w1Lq[1][r];
        }
        acc0 = __builtin_amdgcn_mfma_f32_16x16x32_bf16(w1f[0][0].v, a0.v, acc0, 0, 0, 0);
        acc0 = __builtin_amdgcn_mfma_f32_16x16x32_bf16(w1f[0][1].v, a1.v, acc0, 0, 0, 0);
        acc1 = __builtin_amdgcn_mfma_f32_16x16x32_bf16(w1f[1][0].v, a0.v, acc1, 0, 0, 0);
        acc1 = __builtin_amdgcn_mfma_f32_16x16x32_bf16(w1f[1][1].v, a1.v, acc1, 0, 0, 0);

        uint u0 = pk2(sigmoidf_(acc0[0]), sigmoidf_(acc0[1]));
        uint u1 = pk2(sigmoidf_(acc0[2]), sigmoidf_(acc0[3]));
        uint u2 = pk2(sigmoidf_(acc1[0]), sigmoidf_(acc1[1]));
        uint u3 = pk2(sigmoidf_(acc1[2]), sigmoidf_(acc1[3]));
        uint2 p01 = {u0, u1}, p23 = {u2, u3};
        *(uint2*)&hbuf[w][n16 * 40 + q * 4]      = p01;
        *(uint2*)&hbuf[w][n16 * 40 + 16 + q * 4] = p23;

        Frag ha;
        *(uint4*)&ha.u[0] = *(const uint4*)&hbuf[w][n16 * 40 + q * 8];

        f32x4 c0, c1;
#pragma unroll
        for (int r = 0; r < 4; r++) { c0[r] = b2q[0][r]; c1[r] = b2q[1][r]; }
        c0 = __builtin_amdgcn_mfma_f32_16x16x32_bf16(w2f[0].v, ha.v, c0, 0, 0, 0);
        c1 = __builtin_amdgcn_mfma_f32_16x16x32_bf16(w2f[1].v, ha.v, c1, 0, 0, 0);

        uint g0 = pk2(sigmoidf_(c0[0]), sigmoidf_(c0[1]));
        uint g1 = pk2(sigmoidf_(c0[2]), sigmoidf_(c0[3]));
        uint g2 = pk2(sigmoidf_(c1[0]), sigmoidf_(c1[1]));
        uint g3 = pk2(sigmoidf_(c1[2]), sigmoidf_(c1[3]));
        if (vrow) {
            uint* base = (uint*)(h + (size_t)(e0 * 4 + n16) * H2_F);
            base[q * 2]     = g0;
            base[q * 2 + 1] = g1;
            base[8 + q * 2] = g2;
            if (q < 3) base[8 + q * 2 + 1] = g3;
        }
    }
}

__global__ void __launch_bounds__(256) gather_final(
    const ushort* __restrict__ h, const int* __restrict__ list,
    const int* __restrict__ offs, const float* __restrict__ W3,
    const float* __restrict__ b3, float* __restrict__ out, int N) {
    __shared__ float sW3[H2_F * 32];
    __shared__ float sb3[32];
    __shared__ float sacc[4][B_SZ][H2_F];
    for (int i = threadIdx.x; i < H2_F * 32; i += 256) sW3[i] = W3[i];
    if (threadIdx.x < 32) sb3[threadIdx.x] = b3[threadIdx.x];
    __syncthreads();

    int w = threadIdx.x >> 6, lane = threadIdx.x & 63;
    int n = blockIdx.x * 4 + w;
    if (n >= N) return;

    if (lane < 60) {
        int bq = lane / 15, jp = lane % 15;
        float a0 = 0.f, a1 = 0.f;
        int s = offs[n], e = offs[n + 1];
        int i = s;
        for (; i + 4 <= e; i += 4) {
            int v0 = list[i], v1 = list[i + 1], v2 = list[i + 2], v3 = list[i + 3];
            uint d0 = *(const uint*)(h + (size_t)(v0 & 0x7FFFFFFF) * 120 + bq * 30 + jp * 2);
            uint d1 = *(const uint*)(h + (size_t)(v1 & 0x7FFFFFFF) * 120 + bq * 30 + jp * 2);
            uint d2 = *(const uint*)(h + (size_t)(v2 & 0x7FFFFFFF) * 120 + bq * 30 + jp * 2);
            uint d3 = *(const uint*)(h + (size_t)(v3 & 0x7FFFFFFF) * 120 + bq * 30 + jp * 2);
            float g0 = (v0 < 0) ? -1.f : 1.f;
            float g1 = (v1 < 0) ? -1.f : 1.f;
            float g2 = (v2 < 0) ? -1.f : 1.f;
            float g3 = (v3 < 0) ? -1.f : 1.f;
            a0 += g0 * bf2f((ushort)d0) + g1 * bf2f((ushort)d1)
                + g2 * bf2f((ushort)d2) + g3 * bf2f((ushort)d3);
            a1 += g0 * bf2f((ushort)(d0 >> 16)) + g1 * bf2f((ushort)(d1 >> 16))
                + g2 * bf2f((ushort)(d2 >> 16)) + g3 * bf2f((ushort)(d3 >> 16));
        }
        for (; i < e; i++) {
            int v = list[i];
            uint d = *(const uint*)(h + (size_t)(v & 0x7FFFFFFF) * 120 + bq * 30 + jp * 2);
            float g = (v < 0) ? -1.f : 1.f;
            a0 += g * bf2f((ushort)d);
            a1 += g * bf2f((ushort)(d >> 16));
        }
        sacc[w][bq][jp * 2]     = a0;
        sacc[w][bq][jp * 2 + 1] = a1;
    }
    int b = lane >> 4, k = lane & 15;
    float o0 = sb3[k], o1 = sb3[k + 16];
#pragma unroll
    for (int j = 0; j < H2_F; j++) {
        float v = sacc[w][b][j];
        o0 += v * sW3[j * 32 + k];
        o1 += v * sW3[j * 32 + k + 16];
    }
    float* op = out + ((size_t)b * N + n) * 32;
    op[k]      = sigmoidf_(o0);
    op[k + 16] = sigmoidf_(o1);
}

// ---------------------------------------------------------------------------
extern "C" void kernel_launch(void* const* d_in, const int* in_sizes, int n_in,
                              void* d_out, int out_size, void* d_ws, size_t ws_size,
                              hipStream_t stream) {
    const float* x  = (const float*)d_in[0];
    const int*   ei = (const int*)d_in[1];
    const float* ea = (const float*)d_in[2];
    const float* W1 = (const float*)d_in[3];
    const float* b1 = (const float*)d_in[4];
    const float* W2 = (const float*)d_in[5];
    const float* b2 = (const float*)d_in[6];
    const float* W3 = (const float*)d_in[7];
    const float* b3 = (const float*)d_in[8];
    float* out = (float*)d_out;

    const int E  = in_sizes[2];
    const int N  = in_sizes[0] / (B_SZ * IN_F);
    const int BN = B_SZ * N;
    const int nb = (N + 1023) / 1024;
    const int tiles = (E + 3) / 4;
    const int waves = (tiles + TPW - 1) / TPW;
    const int eblocks = (waves + 3) / 4;

    // ---- tier A layout: slot-direct h (2E slots x 240 B) ----
    char* base = (char*)d_ws;
    size_t off = 0;
    int* cnt    = (int*)(base + off); off += (size_t)N * 4;
    float* sums = (float*)(base + off); off += 8;
    int* offs   = (int*)(base + off); off += (size_t)(N + 1) * 4;
    int* cursor = (int*)(base + off); off += (size_t)N * 4;
    int* bsum   = (int*)(base + off); off += 4096;
    off = (off + 255) & ~(size_t)255;
    ushort* h   = (ushort*)(base + off); off += (size_t)2 * E * 240;
    off = (off + 255) & ~(size_t)255;
    ushort* xb  = (ushort*)(base + off); off += (size_t)BN * IN_F * 2;
    size_t needA = off;

    // ---- tier B layout (round-4): list + e-indexed h ----
    size_t offB = 0;
    int* cntB    = (int*)(base + offB); offB += (size_t)N * 4;
    float* sumsB = (float*)(base + offB); offB += 8;
    int* offsB   = (int*)(base + offB); offB += (size_t)(N + 1) * 4;
    int* cursorB = (int*)(base + offB); offB += (size_t)N * 4;
    int* bsumB   = (int*)(base + offB); offB += 4096;
    int* list    = (int*)(base + offB); offB += (size_t)2 * E * 4;
    offB = (offB + 255) & ~(size_t)255;
    ushort* hB   = (ushort*)(base + offB); offB += (size_t)E * 240;
    offB = (offB + 255) & ~(size_t)255;
    ushort* xbB  = (ushort*)(base + offB);
    size_t needB_noxb = offB;
    size_t needB = offB + (size_t)BN * IN_F * 2;

    if (ws_size >= needA) {
        hipMemsetAsync(cnt, 0, (size_t)N * 4 + 8, stream);  // cnt + sums
        stats_hist_kernel<<<(E + 255) / 256, 256, 0, stream>>>(ea, ei, sums, cnt, E, N);
        long long n8 = (long long)BN * IN_F / 8;
        xcvt_kernel<<<(int)((n8 + 255) / 256), 256, 0, stream>>>(x, xb, n8);
        scan1_kernel<<<nb, 256, 0, stream>>>(cnt, offs, bsum, N);
        scan2_kernel<<<1, 64, 0, stream>>>(bsum, offs, nb, N);
        scan3_kernel<<<nb, 256, 0, stream>>>(offs, cursor, bsum, N);
        edge_mlp_mfma3<<<eblocks, 256, 0, stream>>>(xb, ei, ea, W1, b1, W2, b2,
                                                    sums, cursor, h, E, N, tiles);
        gather_final2<<<(N + 3) / 4, 256, 0, stream>>>(h, offs, W3, b3, out, N);
    } else {
        bool use_xb = (ws_size >= needB);
        hipMemsetAsync(cntB, 0, (size_t)N * 4 + 8, stream);
        stats_hist_kernel<<<(E + 255) / 256, 256, 0, stream>>>(ea, ei, sumsB, cntB, E, N);
        if (use_xb) {
            long long n8 = (long long)BN * IN_F / 8;
            xcvt_kernel<<<(int)((n8 + 255) / 256), 256, 0, stream>>>(x, xbB, n8);
        }
        scan1_kernel<<<nb, 256, 0, stream>>>(cntB, offsB, bsumB, N);
        scan2_kernel<<<1, 64, 0, stream>>>(bsumB, offsB, nb, N);
        scan3_kernel<<<nb, 256, 0, stream>>>(offsB, cursorB, bsumB, N);
        scatter_kernel<<<(E + 255) / 256, 256, 0, stream>>>(ei, cursorB, list, E, N);
        if (use_xb)
            edge_mlp_mfma2<true><<<eblocks, 256, 0, stream>>>(x, xbB, ei, ea, W1, b1,
                                                              W2, b2, sumsB, hB, E, N, tiles);
        else
            edge_mlp_mfma2<false><<<eblocks, 256, 0, stream>>>(x, xbB, ei, ea, W1, b1,
                                                               W2, b2, sumsB, hB, E, N, tiles);
        gather_final<<<(N + 3) / 4, 256, 0, stream>>>(hB, list, offsB, W3, b3, out, N);
        (void)needB_noxb;
    }
}

// Round 6
// 561.650 us; speedup vs baseline: 17.2787x; 1.0150x over previous
//
#include <hip/hip_runtime.h>
#include <math.h>

#define B_SZ 4
#define IN_F 32
#define H1_F 32
#define H2_F 30
#define TPW 16   // tiles per wave in edge kernel

typedef unsigned int uint;
typedef unsigned short ushort;
typedef __attribute__((ext_vector_type(8))) short bf16x8;
typedef __attribute__((ext_vector_type(4))) float f32x4;

__device__ __forceinline__ float fastrcp(float x) {
#if __has_builtin(__builtin_amdgcn_rcpf)
    return __builtin_amdgcn_rcpf(x);
#else
    return 1.f / x;
#endif
}
__device__ __forceinline__ float sigmoidf_(float x) {
    return fastrcp(1.f + __expf(-x));
}

__device__ __forceinline__ ushort f2bf(float f) {
    uint u = __float_as_uint(f);
    return (ushort)((u + 0x7FFFu + ((u >> 16) & 1u)) >> 16);  // RNE
}
__device__ __forceinline__ float bf2f(ushort v) { return __uint_as_float(((uint)v) << 16); }
__device__ __forceinline__ uint pk2(float a, float b) {
    return (uint)f2bf(a) | ((uint)f2bf(b) << 16);
}

union Frag { bf16x8 v; ushort us[8]; uint u[4]; };

// ---------------------------------------------------------------------------
// fused stats (mean/sumsq of ea) + degree histogram (tgt+src combined)
// ---------------------------------------------------------------------------
__global__ void __launch_bounds__(256) stats_hist_kernel(
    const float* __restrict__ ea, const int* __restrict__ ei,
    float* __restrict__ sums, int* __restrict__ cnt, int E, int N) {
    int e = blockIdx.x * 256 + threadIdx.x;
    float a = (e < E) ? ea[e] : 0.f;
    if (e < E) {
        atomicAdd(&cnt[ei[E + e]], 1);
        atomicAdd(&cnt[ei[e]], 1);
    }
    float v = a, v2 = a * a;
    for (int off = 32; off > 0; off >>= 1) {
        v  += __shfl_down(v, off);
        v2 += __shfl_down(v2, off);
    }
    __shared__ float s1[4], s2[4];
    int wid = threadIdx.x >> 6, lane = threadIdx.x & 63;
    if (lane == 0) { s1[wid] = v; s2[wid] = v2; }
    __syncthreads();
    if (threadIdx.x == 0) {
        unsafeAtomicAdd(&sums[0], s1[0] + s1[1] + s1[2] + s1[3]);
        unsafeAtomicAdd(&sums[1], s2[0] + s2[1] + s2[2] + s2[3]);
    }
}

// ---------------------------------------------------------------------------
// x f32 -> bf16 conversion (8 elems/thread)
// ---------------------------------------------------------------------------
__global__ void __launch_bounds__(256) xcvt_kernel(const float* __restrict__ x,
                                                   ushort* __restrict__ xb,
                                                   long long n8) {
    long long i = (long long)blockIdx.x * 256 + threadIdx.x;
    if (i >= n8) return;
    const float4* p = (const float4*)(x + i * 8);
    float4 v0 = p[0], v1 = p[1];
    uint4 o;
    o.x = pk2(v0.x, v0.y); o.y = pk2(v0.z, v0.w);
    o.z = pk2(v1.x, v1.y); o.w = pk2(v1.z, v1.w);
    *(uint4*)(xb + i * 8) = o;
}

// ---------------------------------------------------------------------------
// 3-phase multi-block exclusive scan (1024 elems/block)
// ---------------------------------------------------------------------------
__global__ void __launch_bounds__(256) scan1_kernel(const int* __restrict__ cnt,
                                                    int* __restrict__ offs,
                                                    int* __restrict__ bsum, int n) {
    __shared__ int wtot[4];
    int base = blockIdx.x * 1024 + threadIdx.x * 4;
    int4 v = {0, 0, 0, 0};
    if (base + 3 < n) v = *(const int4*)(cnt + base);
    else {
        if (base < n)     v.x = cnt[base];
        if (base + 1 < n) v.y = cnt[base + 1];
        if (base + 2 < n) v.z = cnt[base + 2];
        if (base + 3 < n) v.w = cnt[base + 3];
    }
    int s = v.x + v.y + v.z + v.w;
    int incl = s;
    int lane = threadIdx.x & 63;
    for (int d = 1; d < 64; d <<= 1) {
        int t = __shfl_up(incl, d);
        if (lane >= d) incl += t;
    }
    int wid = threadIdx.x >> 6;
    if (lane == 63) wtot[wid] = incl;
    __syncthreads();
    int woff = 0, tot = 0;
#pragma unroll
    for (int w = 0; w < 4; w++) {
        int t = wtot[w];
        if (w < wid) woff += t;
        tot += t;
    }
    int excl = woff + incl - s;
    int4 o;
    o.x = excl; o.y = excl + v.x; o.z = o.y + v.y; o.w = o.z + v.z;
    if (base + 3 < n) *(int4*)(offs + base) = o;
    else {
        if (base < n)     offs[base] = o.x;
        if (base + 1 < n) offs[base + 1] = o.y;
        if (base + 2 < n) offs[base + 2] = o.z;
        if (base + 3 < n) offs[base + 3] = o.w;
    }
    if (threadIdx.x == 0) bsum[blockIdx.x] = tot;
}

__global__ void scan2_kernel(int* __restrict__ bsum, int* __restrict__ offs,
                             int nb, int n) {
    int lane = threadIdx.x;
    if (nb <= 64) {
        int v = (lane < nb) ? bsum[lane] : 0;
        int incl = v;
        for (int d = 1; d < 64; d <<= 1) {
            int t = __shfl_up(incl, d);
            if (lane >= d) incl += t;
        }
        if (lane < nb) bsum[lane] = incl - v;
        if (lane == 63) offs[n] = incl;
    } else if (lane == 0) {
        int run = 0;
        for (int i = 0; i < nb; i++) { int t = bsum[i]; bsum[i] = run; run += t; }
        offs[n] = run;
    }
}

__global__ void __launch_bounds__(256) scan3_kernel(int* __restrict__ offs,
                                                    int* __restrict__ cursor,
                                                    const int* __restrict__ bsum, int n) {
    int base = blockIdx.x * 1024 + threadIdx.x * 4;
    int add = bsum[blockIdx.x];
    if (base + 3 < n) {
        int4 v = *(const int4*)(offs + base);
        v.x += add; v.y += add; v.z += add; v.w += add;
        *(int4*)(offs + base) = v;
        *(int4*)(cursor + base) = v;
    } else {
        for (int k = 0; k < 4; k++) {
            int i = base + k;
            if (i < n) { int v = offs[i] + add; offs[i] = v; cursor[i] = v; }
        }
    }
}

__global__ void __launch_bounds__(256) restore_cursor_kernel(
    const int* __restrict__ offs, int* __restrict__ cursor, int n) {
    int i = blockIdx.x * 256 + threadIdx.x;
    if (i < n) cursor[i] = offs[i];
}

// ---------------------------------------------------------------------------
// Edge MLP (operand-swapped MFMA), TWO-BATCH pass, writing +/-h directly into
// CSR slots. Tile = 8 edges x 2 batches = 16 rows; row n16 = e_local*2+b_local.
// Slot payload: [b_local(2)][30] bf16 = 120 B. Cursor atomics pipelined 1 tile
// ahead (lanes 0..15: el=lane>>1, side=lane&1; side0=tgt(+), side1=src(-)).
// ---------------------------------------------------------------------------
__global__ void __launch_bounds__(256) edge_mlp_slot(
    const ushort* __restrict__ xb,
    const int* __restrict__ ei, const float* __restrict__ ea,
    const float* __restrict__ W1, const float* __restrict__ b1,
    const float* __restrict__ W2, const float* __restrict__ b2,
    const float* __restrict__ sums, int* __restrict__ cursor,
    ushort* __restrict__ h, int E, int N, int tiles, int boff) {
    __shared__ ushort __attribute__((aligned(16))) hbuf[4][16 * 40];
    int w = threadIdx.x >> 6;
    int lane = threadIdx.x & 63;
    int n16 = lane & 15;
    int q = lane >> 4;

    // weight fragments as operand A (= W^T)
    Frag w1f[2][2];
#pragma unroll
    for (int t = 0; t < 2; t++)
#pragma unroll
        for (int s = 0; s < 2; s++)
#pragma unroll
            for (int j = 0; j < 4; j++) {
                int k0 = 32 * s + q * 8 + 2 * j;
                w1f[t][s].u[j] = pk2(W1[(size_t)k0 * 32 + 16 * t + n16],
                                     W1[(size_t)(k0 + 1) * 32 + 16 * t + n16]);
            }
    Frag w2f[2];
#pragma unroll
    for (int t = 0; t < 2; t++) {
        int m = 16 * t + n16;
#pragma unroll
        for (int j = 0; j < 4; j++) {
            int k0 = q * 8 + 2 * j;
            float a = (m < H2_F) ? W2[(size_t)k0 * H2_F + m] : 0.f;
            float d = (m < H2_F) ? W2[(size_t)(k0 + 1) * H2_F + m] : 0.f;
            w2f[t].u[j] = pk2(a, d);
        }
    }
    float b1q[2][4], w1Lq[2][4], b2q[2][4];
#pragma unroll
    for (int t = 0; t < 2; t++)
#pragma unroll
        for (int r = 0; r < 4; r++) {
            int col = 16 * t + q * 4 + r;
            b1q[t][r]  = b1[col];
            w1Lq[t][r] = W1[(size_t)64 * 32 + col];
            b2q[t][r]  = (col < H2_F) ? b2[col] : 0.f;
        }

    float mean = sums[0] / (float)E;
    float var = (sums[1] - (float)E * mean * mean) / (float)(E - 1);
    float istd = rsqrtf(var);

    int el = n16 >> 1;            // edge offset within tile for this row
    int bl = n16 & 1;             // batch-local
    int b  = bl + boff;           // global batch
    int gw = blockIdx.x * 4 + w;
    int tile0 = gw * TPW;
    if (tile0 >= tiles) return;

    // ---- pipeline: meta + frags + slot atomics one tile ahead ----
    int src, tgt; float eav; bool vrow; Frag a0, a1; int slotraw;
    {
        int eA = tile0 * 8 + el; vrow = eA < E; int c = vrow ? eA : E - 1;
        src = ei[c]; tgt = ei[E + c]; eav = (ea[c] - mean) * istd;
        *(uint4*)&a0.u[0] = *(const uint4*)(xb + ((size_t)b * N + src) * IN_F + q * 8);
        *(uint4*)&a1.u[0] = *(const uint4*)(xb + ((size_t)b * N + tgt) * IN_F + q * 8);
        slotraw = 0;
        if (lane < 16 && vrow)   // lane<16: n16==lane, el=lane>>1, side=lane&1
            slotraw = atomicAdd(&cursor[(lane & 1) ? src : tgt], 1);
    }

    for (int tix = 0; tix < TPW; ++tix) {
        int tile = tile0 + tix;
        if (tile >= tiles) break;

        // prefetch next tile
        int nsrc = 0, ntgt = 0; float neav = 0.f; bool nvrow = false; int nslot = 0;
        Frag na0, na1;
        na0.u[0] = na0.u[1] = na0.u[2] = na0.u[3] = 0; na1 = na0;
        bool hn = (tix + 1 < TPW) && (tile + 1 < tiles);
        if (hn) {
            int eA = (tile + 1) * 8 + el; nvrow = eA < E; int c = nvrow ? eA : E - 1;
            nsrc = ei[c]; ntgt = ei[E + c]; neav = (ea[c] - mean) * istd;
            *(uint4*)&na0.u[0] = *(const uint4*)(xb + ((size_t)b * N + nsrc) * IN_F + q * 8);
            *(uint4*)&na1.u[0] = *(const uint4*)(xb + ((size_t)b * N + ntgt) * IN_F + q * 8);
            if (lane < 16 && nvrow)
                nslot = atomicAdd(&cursor[(lane & 1) ? nsrc : ntgt], 1);
        }

        // ---- compute current tile ----
        f32x4 acc0, acc1;
#pragma unroll
        for (int r = 0; r < 4; r++) {
            acc0[r] = b1q[0][r] + eav * w1Lq[0][r];
            acc1[r] = b1q[1][r] + eav * w1Lq[1][r];
        }
        acc0 = __builtin_amdgcn_mfma_f32_16x16x32_bf16(w1f[0][0].v, a0.v, acc0, 0, 0, 0);
        acc0 = __builtin_amdgcn_mfma_f32_16x16x32_bf16(w1f[0][1].v, a1.v, acc0, 0, 0, 0);
        acc1 = __builtin_amdgcn_mfma_f32_16x16x32_bf16(w1f[1][0].v, a0.v, acc1, 0, 0, 0);
        acc1 = __builtin_amdgcn_mfma_f32_16x16x32_bf16(w1f[1][1].v, a1.v, acc1, 0, 0, 0);

        uint u0 = pk2(sigmoidf_(acc0[0]), sigmoidf_(acc0[1]));
        uint u1 = pk2(sigmoidf_(acc0[2]), sigmoidf_(acc0[3]));
        uint u2 = pk2(sigmoidf_(acc1[0]), sigmoidf_(acc1[1]));
        uint u3 = pk2(sigmoidf_(acc1[2]), sigmoidf_(acc1[3]));
        uint2 p01 = {u0, u1}, p23 = {u2, u3};
        *(uint2*)&hbuf[w][n16 * 40 + q * 4]      = p01;
        *(uint2*)&hbuf[w][n16 * 40 + 16 + q * 4] = p23;

        Frag ha;
        *(uint4*)&ha.u[0] = *(const uint4*)&hbuf[w][n16 * 40 + q * 8];

        f32x4 c0, c1;
#pragma unroll
        for (int r = 0; r < 4; r++) { c0[r] = b2q[0][r]; c1[r] = b2q[1][r]; }
        c0 = __builtin_amdgcn_mfma_f32_16x16x32_bf16(w2f[0].v, ha.v, c0, 0, 0, 0);
        c1 = __builtin_amdgcn_mfma_f32_16x16x32_bf16(w2f[1].v, ha.v, c1, 0, 0, 0);

        uint g0 = pk2(sigmoidf_(c0[0]), sigmoidf_(c0[1]));
        uint g1 = pk2(sigmoidf_(c0[2]), sigmoidf_(c0[3]));
        uint g2 = pk2(sigmoidf_(c1[0]), sigmoidf_(c1[1]));
        uint g3 = pk2(sigmoidf_(c1[2]), sigmoidf_(c1[3]));  // q==3: cols 30,31 invalid

        int slot_t = __shfl(slotraw, el * 2);
        int slot_s = __shfl(slotraw, el * 2 + 1);
        if (vrow) {
            uint* bt = (uint*)(h + (size_t)slot_t * 60 + bl * 30);
            bt[q * 2]     = g0;
            bt[q * 2 + 1] = g1;
            bt[8 + q * 2] = g2;
            if (q < 3) bt[8 + q * 2 + 1] = g3;
            const uint SM = 0x80008000u;
            uint* bs = (uint*)(h + (size_t)slot_s * 60 + bl * 30);
            bs[q * 2]     = g0 ^ SM;
            bs[q * 2 + 1] = g1 ^ SM;
            bs[8 + q * 2] = g2 ^ SM;
            if (q < 3) bs[8 + q * 2 + 1] = g3 ^ SM;
        }

        src = nsrc; tgt = ntgt; eav = neav; vrow = nvrow;
        a0 = na0; a1 = na1; slotraw = nslot;
    }
}

// ---------------------------------------------------------------------------
// Gather over CONTIGUOUS slots (signs baked in), 2-batch pass, fused W3.
// One wave per node. Lanes 0..29 accumulate (bl=lane/15, col-pair jp=lane%15),
// epilogue: all 64 lanes -> 2 batches x 32 outputs.
// ---------------------------------------------------------------------------
__global__ void __launch_bounds__(256) gather_slot(
    const ushort* __restrict__ h, const int* __restrict__ offs,
    const float* __restrict__ W3, const float* __restrict__ b3,
    float* __restrict__ out, int N, int boff) {
    __shared__ float sW3[H2_F * 32];
    __shared__ float sb3[32];
    __shared__ float sacc[4][2][H2_F];
    for (int i = threadIdx.x; i < H2_F * 32; i += 256) sW3[i] = W3[i];
    if (threadIdx.x < 32) sb3[threadIdx.x] = b3[threadIdx.x];
    __syncthreads();

    int w = threadIdx.x >> 6, lane = threadIdx.x & 63;
    int n = blockIdx.x * 4 + w;
    if (n >= N) return;

    int s = offs[n], e = offs[n + 1];
    if (lane < 30) {
        int bl = lane / 15, jp = lane % 15;
        const uint* p = (const uint*)h + (size_t)s * 30 + bl * 15 + jp;
        float a0 = 0.f, a1 = 0.f;
        int cnt = e - s;
        int i = 0;
        for (; i + 4 <= cnt; i += 4) {
            uint d0 = p[0], d1 = p[30], d2 = p[60], d3 = p[90];
            p += 120;
            a0 += bf2f((ushort)d0) + bf2f((ushort)d1)
                + bf2f((ushort)d2) + bf2f((ushort)d3);
            a1 += bf2f((ushort)(d0 >> 16)) + bf2f((ushort)(d1 >> 16))
                + bf2f((ushort)(d2 >> 16)) + bf2f((ushort)(d3 >> 16));
        }
        for (; i < cnt; i++) {
            uint d = p[0];
            p += 30;
            a0 += bf2f((ushort)d);
            a1 += bf2f((ushort)(d >> 16));
        }
        sacc[w][bl][jp * 2]     = a0;
        sacc[w][bl][jp * 2 + 1] = a1;
    }
    // wave-synchronous epilogue: 2 batches x 32 cols = 64 lanes
    int bl = lane >> 5, k = lane & 31;
    float o = sb3[k];
#pragma unroll
    for (int j = 0; j < H2_F; j++) o += sacc[w][bl][j] * sW3[j * 32 + k];
    out[((size_t)(boff + bl) * N + n) * 32 + k] = sigmoidf_(o);
}

// ---------------------------------------------------------------------------
// FALLBACK tier (round-5 path): scatter list + list-indirect gather
// ---------------------------------------------------------------------------
__global__ void __launch_bounds__(256) scatter_kernel(const int* __restrict__ ei,
                                                      int* __restrict__ cursor,
                                                      int* __restrict__ list, int E, int N) {
    int e = blockIdx.x * 256 + threadIdx.x;
    if (e < E) {
        int tgt = ei[E + e];
        int p = atomicAdd(&cursor[tgt], 1);
        list[p] = e;
        int src = ei[e];
        int q = atomicAdd(&cursor[src], 1);
        list[q] = e | (int)0x80000000u;
    }
}

template<bool USE_XB>
__global__ void __launch_bounds__(256) edge_mlp_mfma2(
    const float* __restrict__ x, const ushort* __restrict__ xb,
    const int* __restrict__ ei, const float* __restrict__ ea,
    const float* __restrict__ W1, const float* __restrict__ b1,
    const float* __restrict__ W2, const float* __restrict__ b2,
    const float* __restrict__ sums, ushort* __restrict__ h,
    int E, int N, int tiles) {
    __shared__ ushort __attribute__((aligned(16))) hbuf[4][16 * 40];
    int w = threadIdx.x >> 6;
    int lane = threadIdx.x & 63;
    int n16 = lane & 15;
    int q = lane >> 4;

    Frag w1f[2][2];
#pragma unroll
    for (int t = 0; t < 2; t++)
#pragma unroll
        for (int s = 0; s < 2; s++)
#pragma unroll
            for (int j = 0; j < 4; j++) {
                int k0 = 32 * s + q * 8 + 2 * j;
                w1f[t][s].u[j] = pk2(W1[(size_t)k0 * 32 + 16 * t + n16],
                                     W1[(size_t)(k0 + 1) * 32 + 16 * t + n16]);
            }
    Frag w2f[2];
#pragma unroll
    for (int t = 0; t < 2; t++) {
        int m = 16 * t + n16;
#pragma unroll
        for (int j = 0; j < 4; j++) {
            int k0 = q * 8 + 2 * j;
            float a = (m < H2_F) ? W2[(size_t)k0 * H2_F + m] : 0.f;
            float d = (m < H2_F) ? W2[(size_t)(k0 + 1) * H2_F + m] : 0.f;
            w2f[t].u[j] = pk2(a, d);
        }
    }
    float b1q[2][4], w1Lq[2][4], b2q[2][4];
#pragma unroll
    for (int t = 0; t < 2; t++)
#pragma unroll
        for (int r = 0; r < 4; r++) {
            int col = 16 * t + q * 4 + r;
            b1q[t][r]  = b1[col];
            w1Lq[t][r] = W1[(size_t)64 * 32 + col];
            b2q[t][r]  = (col < H2_F) ? b2[col] : 0.f;
        }

    float mean = sums[0] / (float)E;
    float var = (sums[1] - (float)E * mean * mean) / (float)(E - 1);
    float istd = rsqrtf(var);

    int b = n16 & 3;
    int eoff = n16 >> 2;
    int gw = blockIdx.x * 4 + w;

    for (int tix = 0; tix < TPW; ++tix) {
        int tile = gw * TPW + tix;
        if (tile >= tiles) break;
        int e0 = tile * 4;
        int eA = e0 + eoff;
        bool vrow = eA < E;
        int eAc = vrow ? eA : E - 1;
        int src = ei[eAc], tgt = ei[E + eAc];
        float eav = (ea[eAc] - mean) * istd;

        Frag a0, a1;
        if (USE_XB) {
            *(uint4*)&a0.u[0] = *(const uint4*)(xb + ((size_t)b * N + src) * IN_F + q * 8);
            *(uint4*)&a1.u[0] = *(const uint4*)(xb + ((size_t)b * N + tgt) * IN_F + q * 8);
        } else {
            const float4* ps = (const float4*)(x + ((size_t)b * N + src) * IN_F + q * 8);
            float4 s0 = ps[0], s1 = ps[1];
            const float4* pt = (const float4*)(x + ((size_t)b * N + tgt) * IN_F + q * 8);
            float4 t0 = pt[0], t1 = pt[1];
            a0.u[0] = pk2(s0.x, s0.y); a0.u[1] = pk2(s0.z, s0.w);
            a0.u[2] = pk2(s1.x, s1.y); a0.u[3] = pk2(s1.z, s1.w);
            a1.u[0] = pk2(t0.x, t0.y); a1.u[1] = pk2(t0.z, t0.w);
            a1.u[2] = pk2(t1.x, t1.y); a1.u[3] = pk2(t1.z, t1.w);
        }

        f32x4 acc0, acc1;
#pragma unroll
        for (int r = 0; r < 4; r++) {
            acc0[r] = b1q[0][r] + eav * w1Lq[0][r];
            acc1[r] = b1q[1][r] + eav * w1Lq[1][r];
        }
        acc0 = __builtin_amdgcn_mfma_f32_16x16x32_bf16(w1f[0][0].v, a0.v, acc0, 0, 0, 0);
        acc0 = __builtin_amdgcn_mfma_f32_16x16x32_bf16(w1f[0][1].v, a1.v, acc0, 0, 0, 0);
        acc1 = __builtin_amdgcn_mfma_f32_16x16x32_bf16(w1f[1][0].v, a0.v, acc1, 0, 0, 0);
        acc1 = __builtin_amdgcn_mfma_f32_16x16x32_bf16(w1f[1][1].v, a1.v, acc1, 0, 0, 0);

        uint u0 = pk2(sigmoidf_(acc0[0]), sigmoidf_(acc0[1]));
        uint u1 = pk2(sigmoidf_(acc0[2]), sigmoidf_(acc0[3]));
        uint u2 = pk2(sigmoidf_(acc1[0]), sigmoidf_(acc1[1]));
        uint u3 = pk2(sigmoidf_(acc1[2]), sigmoidf_(acc1[3]));
        uint2 p01 = {u0, u1}, p23 = {u2, u3};
        *(uint2*)&hbuf[w][n16 * 40 + q * 4]      = p01;
        *(uint2*)&hbuf[w][n16 * 40 + 16 + q * 4] = p23;

        Frag ha;
        *(uint4*)&ha.u[0] = *(const uint4*)&hbuf[w][n16 * 40 + q * 8];

        f32x4 c0, c1;
#pragma unroll
        for (int r = 0; r < 4; r++) { c0[r] = b2q[0][r]; c1[r] = b2q[1][r]; }
        c0 = __builtin_amdgcn_mfma_f32_16x16x32_bf16(w2f[0].v, ha.v, c0, 0, 0, 0);
        c1 = __builtin_amdgcn_mfma_f32_16x16x32_bf16(w2f[1].v, ha.v, c1, 0, 0, 0);

        uint g0 = pk2(sigmoidf_(c0[0]), sigmoidf_(c0[1]));
        uint g1 = pk2(sigmoidf_(c0[2]), sigmoidf_(c0[3]));
        uint g2 = pk2(sigmoidf_(c1[0]), sigmoidf_(c1[1]));
        uint g3 = pk2(sigmoidf_(c1[2]), sigmoidf_(c1[3]));
        if (vrow) {
            uint* base = (uint*)(h + (size_t)(e0 * 4 + n16) * H2_F);
            base[q * 2]     = g0;
            base[q * 2 + 1] = g1;
            base[8 + q * 2] = g2;
            if (q < 3) base[8 + q * 2 + 1] = g3;
        }
    }
}

__global__ void __launch_bounds__(256) gather_final(
    const ushort* __restrict__ h, const int* __restrict__ list,
    const int* __restrict__ offs, const float* __restrict__ W3,
    const float* __restrict__ b3, float* __restrict__ out, int N) {
    __shared__ float sW3[H2_F * 32];
    __shared__ float sb3[32];
    __shared__ float sacc[4][B_SZ][H2_F];
    for (int i = threadIdx.x; i < H2_F * 32; i += 256) sW3[i] = W3[i];
    if (threadIdx.x < 32) sb3[threadIdx.x] = b3[threadIdx.x];
    __syncthreads();

    int w = threadIdx.x >> 6, lane = threadIdx.x & 63;
    int n = blockIdx.x * 4 + w;
    if (n >= N) return;

    if (lane < 60) {
        int bq = lane / 15, jp = lane % 15;
        float a0 = 0.f, a1 = 0.f;
        int s = offs[n], e = offs[n + 1];
        int i = s;
        for (; i + 4 <= e; i += 4) {
            int v0 = list[i], v1 = list[i + 1], v2 = list[i + 2], v3 = list[i + 3];
            uint d0 = *(const uint*)(h + (size_t)(v0 & 0x7FFFFFFF) * 120 + bq * 30 + jp * 2);
            uint d1 = *(const uint*)(h + (size_t)(v1 & 0x7FFFFFFF) * 120 + bq * 30 + jp * 2);
            uint d2 = *(const uint*)(h + (size_t)(v2 & 0x7FFFFFFF) * 120 + bq * 30 + jp * 2);
            uint d3 = *(const uint*)(h + (size_t)(v3 & 0x7FFFFFFF) * 120 + bq * 30 + jp * 2);
            float g0 = (v0 < 0) ? -1.f : 1.f;
            float g1 = (v1 < 0) ? -1.f : 1.f;
            float g2 = (v2 < 0) ? -1.f : 1.f;
            float g3 = (v3 < 0) ? -1.f : 1.f;
            a0 += g0 * bf2f((ushort)d0) + g1 * bf2f((ushort)d1)
                + g2 * bf2f((ushort)d2) + g3 * bf2f((ushort)d3);
            a1 += g0 * bf2f((ushort)(d0 >> 16)) + g1 * bf2f((ushort)(d1 >> 16))
                + g2 * bf2f((ushort)(d2 >> 16)) + g3 * bf2f((ushort)(d3 >> 16));
        }
        for (; i < e; i++) {
            int v = list[i];
            uint d = *(const uint*)(h + (size_t)(v & 0x7FFFFFFF) * 120 + bq * 30 + jp * 2);
            float g = (v < 0) ? -1.f : 1.f;
            a0 += g * bf2f((ushort)d);
            a1 += g * bf2f((ushort)(d >> 16));
        }
        sacc[w][bq][jp * 2]     = a0;
        sacc[w][bq][jp * 2 + 1] = a1;
    }
    int b = lane >> 4, k = lane & 15;
    float o0 = sb3[k], o1 = sb3[k + 16];
#pragma unroll
    for (int j = 0; j < H2_F; j++) {
        float v = sacc[w][b][j];
        o0 += v * sW3[j * 32 + k];
        o1 += v * sW3[j * 32 + k + 16];
    }
    float* op = out + ((size_t)b * N + n) * 32;
    op[k]      = sigmoidf_(o0);
    op[k + 16] = sigmoidf_(o1);
}

// ---------------------------------------------------------------------------
extern "C" void kernel_launch(void* const* d_in, const int* in_sizes, int n_in,
                              void* d_out, int out_size, void* d_ws, size_t ws_size,
                              hipStream_t stream) {
    const float* x  = (const float*)d_in[0];
    const int*   ei = (const int*)d_in[1];
    const float* ea = (const float*)d_in[2];
    const float* W1 = (const float*)d_in[3];
    const float* b1 = (const float*)d_in[4];
    const float* W2 = (const float*)d_in[5];
    const float* b2 = (const float*)d_in[6];
    const float* W3 = (const float*)d_in[7];
    const float* b3 = (const float*)d_in[8];
    float* out = (float*)d_out;

    const int E  = in_sizes[2];
    const int N  = in_sizes[0] / (B_SZ * IN_F);
    const int BN = B_SZ * N;
    const int nb = (N + 1023) / 1024;

    char* base = (char*)d_ws;

    // ---- tier NEW: two-pass slot-direct, h = 2E slots x 120 B ----
    size_t off = 0;
    int* cnt    = (int*)(base + off); off += (size_t)N * 4;
    float* sums = (float*)(base + off); off += 8;
    int* offs   = (int*)(base + off); off += (size_t)(N + 1) * 4;
    int* cursor = (int*)(base + off); off += (size_t)N * 4;
    int* bsum   = (int*)(base + off); off += 4096;
    off = (off + 255) & ~(size_t)255;
    ushort* h   = (ushort*)(base + off); off += (size_t)2 * E * 120;
    off = (off + 255) & ~(size_t)255;
    ushort* xb  = (ushort*)(base + off); off += (size_t)BN * IN_F * 2;
    size_t needNew = off;

    // ---- tier B (round-5 fallback): list + e-indexed h ----
    size_t offB = 0;
    int* cntB    = (int*)(base + offB); offB += (size_t)N * 4;
    float* sumsB = (float*)(base + offB); offB += 8;
    int* offsB   = (int*)(base + offB); offB += (size_t)(N + 1) * 4;
    int* cursorB = (int*)(base + offB); offB += (size_t)N * 4;
    int* bsumB   = (int*)(base + offB); offB += 4096;
    int* list    = (int*)(base + offB); offB += (size_t)2 * E * 4;
    offB = (offB + 255) & ~(size_t)255;
    ushort* hB   = (ushort*)(base + offB); offB += (size_t)E * 240;
    offB = (offB + 255) & ~(size_t)255;
    ushort* xbB  = (ushort*)(base + offB);
    size_t needB = offB + (size_t)BN * IN_F * 2;

    if (ws_size >= needNew) {
        const int tiles = (E + 7) / 8;
        const int waves = (tiles + TPW - 1) / TPW;
        const int eblocks = (waves + 3) / 4;
        hipMemsetAsync(cnt, 0, (size_t)N * 4 + 8, stream);  // cnt + sums
        stats_hist_kernel<<<(E + 255) / 256, 256, 0, stream>>>(ea, ei, sums, cnt, E, N);
        long long n8 = (long long)BN * IN_F / 8;
        xcvt_kernel<<<(int)((n8 + 255) / 256), 256, 0, stream>>>(x, xb, n8);
        scan1_kernel<<<nb, 256, 0, stream>>>(cnt, offs, bsum, N);
        scan2_kernel<<<1, 64, 0, stream>>>(bsum, offs, nb, N);
        scan3_kernel<<<nb, 256, 0, stream>>>(offs, cursor, bsum, N);
        // pass 0: batches 0,1
        edge_mlp_slot<<<eblocks, 256, 0, stream>>>(xb, ei, ea, W1, b1, W2, b2,
                                                   sums, cursor, h, E, N, tiles, 0);
        gather_slot<<<(N + 3) / 4, 256, 0, stream>>>(h, offs, W3, b3, out, N, 0);
        // pass 1: batches 2,3
        restore_cursor_kernel<<<(N + 255) / 256, 256, 0, stream>>>(offs, cursor, N);
        edge_mlp_slot<<<eblocks, 256, 0, stream>>>(xb, ei, ea, W1, b1, W2, b2,
                                                   sums, cursor, h, E, N, tiles, 2);
        gather_slot<<<(N + 3) / 4, 256, 0, stream>>>(h, offs, W3, b3, out, N, 2);
    } else {
        const int tiles = (E + 3) / 4;
        const int waves = (tiles + TPW - 1) / TPW;
        const int eblocks = (waves + 3) / 4;
        bool use_xb = (ws_size >= needB);
        hipMemsetAsync(cntB, 0, (size_t)N * 4 + 8, stream);
        stats_hist_kernel<<<(E + 255) / 256, 256, 0, stream>>>(ea, ei, sumsB, cntB, E, N);
        if (use_xb) {
            long long n8 = (long long)BN * IN_F / 8;
            xcvt_kernel<<<(int)((n8 + 255) / 256), 256, 0, stream>>>(x, xbB, n8);
        }
        scan1_kernel<<<nb, 256, 0, stream>>>(cntB, offsB, bsumB, N);
        scan2_kernel<<<1, 64, 0, stream>>>(bsumB, offsB, nb, N);
        scan3_kernel<<<nb, 256, 0, stream>>>(offsB, cursorB, bsumB, N);
        scatter_kernel<<<(E + 255) / 256, 256, 0, stream>>>(ei, cursorB, list, E, N);
        if (use_xb)
            edge_mlp_mfma2<true><<<eblocks, 256, 0, stream>>>(x, xbB, ei, ea, W1, b1,
                                                              W2, b2, sumsB, hB, E, N, tiles);
        else
            edge_mlp_mfma2<false><<<eblocks, 256, 0, stream>>>(x, xbB, ei, ea, W1, b1,
                                                               W2, b2, sumsB, hB, E, N, tiles);
        gather_final<<<(N + 3) / 4, 256, 0, stream>>>(hB, list, offsB, W3, b3, out, N);
    }
}